// Round 10
// baseline (1540.630 us; speedup 1.0000x reference)
//
#include <hip/hip_runtime.h>

#define DIMN 8192
#define SEQ  1024
#define NHEAD 128

typedef __attribute__((ext_vector_type(8))) short bf16x8;
typedef __attribute__((ext_vector_type(4))) float f32x4;

#define MFMA16(a, b, c) __builtin_amdgcn_mfma_f32_16x16x32_bf16((a), (b), (c), 0, 0, 0)

__device__ __forceinline__ unsigned short f2bf(float f) {
  unsigned u = __float_as_uint(f);
  return (unsigned short)((u + 0x7FFFu + ((u >> 16) & 1u)) >> 16);
}
__device__ __forceinline__ unsigned pack2(float a, float b) {
  return (unsigned)f2bf(a) | ((unsigned)f2bf(b) << 16);
}
__device__ __forceinline__ unsigned pack2_rhu(float lo, float hi) {
  unsigned a = __float_as_uint(lo) + 0x8000u;
  unsigned b = __float_as_uint(hi) + 0x8000u;
  return (a >> 16) | (b & 0xFFFF0000u);
}
__device__ __forceinline__ void async_copy16(void* lds_dst, const void* gsrc) {
  __builtin_amdgcn_global_load_lds(
      (const __attribute__((address_space(1))) unsigned int*)gsrc,
      (__attribute__((address_space(3))) unsigned int*)lds_dst, 16, 0, 0);
}

// ---------------- fp32 -> bf16 convert (x) ----------------
__global__ __launch_bounds__(256) void cvt_bf16_kernel(
    const float* __restrict__ in, unsigned short* __restrict__ out) {
  int i = blockIdx.x * 256 + threadIdx.x;
  const float4* p = (const float4*)in;
  float4 a = p[2 * i];
  float4 b = p[2 * i + 1];
  uint4 r;
  r.x = pack2(a.x, a.y);
  r.y = pack2(a.z, a.w);
  r.z = pack2(b.x, b.y);
  r.w = pack2(b.z, b.w);
  ((uint4*)out)[i] = r;
}

// ---------------- GEMM: C[1024,8192] = A(bf16) @ W(f32->bf16) ----------------
// ROUND-9 DIAGNOSIS: latency-bound with insufficient TLP. Five schedules all
// stuck at 277-347us with every pipe <30% busy and 8 waves/CU (2/SIMD) — the
// constant across them. m97 (874 TF, same structure, plain __syncthreads) ran
// 12 waves/CU: its pipelining is INTER-BLOCK (m114: one block drains at its
// barrier while other blocks' waves compute).
// FIX: occupancy. 64x128 tile, 256 thr (4 waves 2x2, 32x64 out each), BK=64,
// double-buffered LDS = 48KB -> 3 blocks/CU (147456B), grid 16x64=1024 blocks,
// launch_bounds(256,3). Simple single-__syncthreads loop (compiler waitcnts;
// 3-block overlap absorbs the barrier drain). B staging: verified R6 geometry
// (32 scalar fp32 + pack_rhu + XOR-slot ds_write_b128, 0 conflicts measured).
// XCD swizzle: XCD x owns n-panels [8x,8x+8), each with all 16 m-sharers
// co-resident -> W k-slabs fetched once per XCD, L2-served to sharers.
template <int WRITE_F32>
__global__ __launch_bounds__(256, 3) void gemm_bf16(
    const unsigned short* __restrict__ A, const float* __restrict__ W,
    void* __restrict__ Cout, float out_scale) {
  __shared__ unsigned short smem[2 * 12288];  // per buf: A[64][64] + B_t[128][64]
  const int t = threadIdx.x;
  const int l = t & 63;
  const int w = t >> 6;                 // 0..3
  const int wm = w >> 1, wn = w & 1;    // 2x2 wave grid
  const int logical = (blockIdx.x & 7) * 128 + (blockIdx.x >> 3);  // XCD swizzle
  const int m0 = (logical & 15) * 64;   // m fastest within an XCD's chunk
  const int n0 = (logical >> 4) * 128;

  // A staging: per wave 2 gload_lds, each 8 rows x 8 slots(16B), XOR-preswizzled src
  const int rin = l >> 3;
  const int aslot = (l & 7) ^ rin;
  // B staging: thread owns col bn, k-rows [bkb, bkb+32)
  const int bn = t & 127;
  const int bkb = (t >> 7) * 32;

  f32x4 acc[2][4];
#pragma unroll
  for (int mb = 0; mb < 2; ++mb)
#pragma unroll
    for (int nb = 0; nb < 4; ++nb) acc[mb][nb] = (f32x4){0.f, 0.f, 0.f, 0.f};

  float fb[32];
  const unsigned short* aptr = A + (size_t)(m0 + w * 16 + rin) * DIMN + aslot * 8;
  const float* wp = W + (size_t)bkb * DIMN + n0 + bn;

  auto load_B = [&]() {
#pragma unroll
    for (int i = 0; i < 32; ++i) fb[i] = wp[(size_t)i * DIMN];
    wp += (size_t)64 * DIMN;
  };
  auto write_B = [&](int buf) {
    unsigned short* bb = &smem[buf * 12288 + 4096];
#pragma unroll
    for (int j = 0; j < 4; ++j) {
      int p = ((bkb >> 3) + j) ^ (bn & 7);  // physical slot (XOR swizzle)
      uint4 val;
      val.x = pack2_rhu(fb[j * 8 + 0], fb[j * 8 + 1]);
      val.y = pack2_rhu(fb[j * 8 + 2], fb[j * 8 + 3]);
      val.z = pack2_rhu(fb[j * 8 + 4], fb[j * 8 + 5]);
      val.w = pack2_rhu(fb[j * 8 + 6], fb[j * 8 + 7]);
      *(uint4*)&bb[bn * 64 + p * 8] = val;
    }
  };
  auto stage_A = [&](int buf) {
#pragma unroll
    for (int i = 0; i < 2; ++i)
      async_copy16(&smem[buf * 12288 + (w * 16 + i * 8) * 64], aptr + (size_t)i * 8 * DIMN);
    aptr += 64;
  };
  auto compute = [&](int buf) {
    const unsigned short* la = &smem[buf * 12288];
    const unsigned short* lb = la + 4096;
#pragma unroll
    for (int kh = 0; kh < 2; ++kh) {
      bf16x8 af[2], bfr[4];
#pragma unroll
      for (int mb = 0; mb < 2; ++mb) {
        int row = wm * 32 + mb * 16 + (l & 15);
        int sl = ((l >> 4) + kh * 4) ^ (row & 7);
        af[mb] = *(const bf16x8*)&la[row * 64 + sl * 8];
      }
#pragma unroll
      for (int nb = 0; nb < 4; ++nb) {
        int row = wn * 64 + nb * 16 + (l & 15);
        int sl = ((l >> 4) + kh * 4) ^ (row & 7);
        bfr[nb] = *(const bf16x8*)&lb[row * 64 + sl * 8];
      }
      __builtin_amdgcn_s_setprio(1);
#pragma unroll
      for (int mb = 0; mb < 2; ++mb)
#pragma unroll
        for (int nb = 0; nb < 4; ++nb)
          acc[mb][nb] = MFMA16(af[mb], bfr[nb], acc[mb][nb]);
      __builtin_amdgcn_s_setprio(0);
    }
  };

  // prologue: tile 0
  load_B();
  stage_A(0);
  write_B(0);
  __syncthreads();

  int buf = 0;
  for (int kt = 0; kt < 128; ++kt) {
    if (kt < 127) {
      load_B();            // issue next-tile B fp32 loads (regs)
      stage_A(buf ^ 1);    // issue next-tile A DMA
    }
    compute(buf);
    if (kt < 127) write_B(buf ^ 1);
    __syncthreads();
    buf ^= 1;
  }

  // epilogue: D layout col=lane&15, row=(lane>>4)*4+reg (m89-verified)
#pragma unroll
  for (int mb = 0; mb < 2; ++mb)
#pragma unroll
    for (int nb = 0; nb < 4; ++nb)
#pragma unroll
      for (int r = 0; r < 4; ++r) {
        int rg = m0 + wm * 32 + mb * 16 + (l >> 4) * 4 + r;
        int cg = n0 + wn * 64 + nb * 16 + (l & 15);
        float vl = acc[mb][nb][r] * out_scale;
        if (WRITE_F32)
          ((float*)Cout)[(size_t)rg * DIMN + cg] = vl;
        else
          ((unsigned short*)Cout)[(size_t)rg * DIMN + cg] = f2bf(vl);
      }
}

// ---------------- fused flash attention (unchanged) ----------------
__global__ __launch_bounds__(256) void attn_kernel(
    const unsigned short* __restrict__ q, const unsigned short* __restrict__ k,
    const unsigned short* __restrict__ v, unsigned short* __restrict__ o) {
  __shared__ unsigned short Qs[64 * 72];
  __shared__ unsigned short Ks[64 * 72];
  __shared__ unsigned short Vt[64 * 72];
  __shared__ unsigned short Ps[4][16 * 72];

  const int t = threadIdx.x, l = t & 63, w = t >> 6;
  const int h = blockIdx.x >> 4;
  const int q0 = (blockIdx.x & 15) * 64;
  const int skey = t >> 2;
  const int sd = (t & 3) * 16;

  {
    const unsigned short* src = q + (size_t)(q0 + skey) * DIMN + h * 64 + sd;
    uint4 a = *(const uint4*)src;
    uint4 b = *(const uint4*)(src + 8);
    *(uint4*)&Qs[skey * 72 + sd] = a;
    *(uint4*)&Qs[skey * 72 + sd + 8] = b;
  }
  __syncthreads();
  bf16x8 qf[2];
#pragma unroll
  for (int kh = 0; kh < 2; ++kh)
    qf[kh] = *(const bf16x8*)&Qs[(w * 16 + (l & 15)) * 72 + (l >> 4) * 8 + kh * 32];

  float m_run[4] = {-1e30f, -1e30f, -1e30f, -1e30f};
  float l_run[4] = {0.f, 0.f, 0.f, 0.f};
  f32x4 oacc[4];
#pragma unroll
  for (int db = 0; db < 4; ++db) oacc[db] = (f32x4){0.f, 0.f, 0.f, 0.f};

  for (int kv = 0; kv < 16; ++kv) {
    __syncthreads();
    {
      const unsigned short* ksrc = k + (size_t)(kv * 64 + skey) * DIMN + h * 64 + sd;
      uint4 a = *(const uint4*)ksrc;
      uint4 b = *(const uint4*)(ksrc + 8);
      *(uint4*)&Ks[skey * 72 + sd] = a;
      *(uint4*)&Ks[skey * 72 + sd + 8] = b;
      const unsigned short* vsrc = v + (size_t)(kv * 64 + skey) * DIMN + h * 64 + sd;
      uint4 c = *(const uint4*)vsrc;
      uint4 d = *(const uint4*)(vsrc + 8);
      const unsigned short* cs = (const unsigned short*)&c;
      const unsigned short* ds = (const unsigned short*)&d;
#pragma unroll
      for (int j = 0; j < 8; ++j) Vt[(sd + j) * 72 + skey] = cs[j];
#pragma unroll
      for (int j = 0; j < 8; ++j) Vt[(sd + 8 + j) * 72 + skey] = ds[j];
    }
    __syncthreads();

    f32x4 sAcc[4];
#pragma unroll
    for (int nb = 0; nb < 4; ++nb) sAcc[nb] = (f32x4){0.f, 0.f, 0.f, 0.f};
#pragma unroll
    for (int kh = 0; kh < 2; ++kh) {
#pragma unroll
      for (int nb = 0; nb < 4; ++nb) {
        bf16x8 kf = *(const bf16x8*)&Ks[(nb * 16 + (l & 15)) * 72 + (l >> 4) * 8 + kh * 32];
        sAcc[nb] = MFMA16(qf[kh], kf, sAcc[nb]);
      }
    }

    float sc[4], mx[4];
#pragma unroll
    for (int r = 0; r < 4; ++r) {
      float mv = fmaxf(fmaxf(sAcc[0][r], sAcc[1][r]), fmaxf(sAcc[2][r], sAcc[3][r]));
      mv = fmaxf(mv, __shfl_xor(mv, 1));
      mv = fmaxf(mv, __shfl_xor(mv, 2));
      mv = fmaxf(mv, __shfl_xor(mv, 4));
      mv = fmaxf(mv, __shfl_xor(mv, 8));
      float mn = fmaxf(m_run[r], mv);
      sc[r] = __expf(m_run[r] - mn);
      m_run[r] = mn;
      mx[r] = mn;
    }
#pragma unroll
    for (int nb = 0; nb < 4; ++nb) {
      f32x4 sv = sAcc[nb];
#pragma unroll
      for (int r = 0; r < 4; ++r) sv[r] = __expf(sv[r] - mx[r]);
      sAcc[nb] = sv;
    }
#pragma unroll
    for (int r = 0; r < 4; ++r) {
      float ls = sAcc[0][r] + sAcc[1][r] + sAcc[2][r] + sAcc[3][r];
      ls += __shfl_xor(ls, 1);
      ls += __shfl_xor(ls, 2);
      ls += __shfl_xor(ls, 4);
      ls += __shfl_xor(ls, 8);
      l_run[r] = l_run[r] * sc[r] + ls;
    }
#pragma unroll
    for (int db = 0; db < 4; ++db) {
      f32x4 ov = oacc[db];
#pragma unroll
      for (int r = 0; r < 4; ++r) ov[r] *= sc[r];
      oacc[db] = ov;
    }

#pragma unroll
    for (int nb = 0; nb < 4; ++nb)
#pragma unroll
      for (int r = 0; r < 4; ++r)
        Ps[w][((l >> 4) * 4 + r) * 72 + nb * 16 + (l & 15)] = f2bf(sAcc[nb][r]);

#pragma unroll
    for (int kh = 0; kh < 2; ++kh) {
      bf16x8 pf = *(const bf16x8*)&Ps[w][(l & 15) * 72 + (l >> 4) * 8 + kh * 32];
#pragma unroll
      for (int db = 0; db < 4; ++db) {
        bf16x8 vf = *(const bf16x8*)&Vt[(db * 16 + (l & 15)) * 72 + (l >> 4) * 8 + kh * 32];
        oacc[db] = MFMA16(pf, vf, oacc[db]);
      }
    }
  }

#pragma unroll
  for (int db = 0; db < 4; ++db)
#pragma unroll
    for (int r = 0; r < 4; ++r) {
      float vl = oacc[db][r] / l_run[r];
      int rg = q0 + w * 16 + (l >> 4) * 4 + r;
      int cg = h * 64 + db * 16 + (l & 15);
      o[(size_t)rg * DIMN + cg] = f2bf(vl);
    }
}

extern "C" void kernel_launch(void* const* d_in, const int* in_sizes, int n_in,
                              void* d_out, int out_size, void* d_ws, size_t ws_size,
                              hipStream_t stream) {
  const float* x  = (const float*)d_in[0];
  const float* wq = (const float*)d_in[1];
  const float* wk = (const float*)d_in[2];
  const float* wv = (const float*)d_in[3];
  const float* wo = (const float*)d_in[4];

  char* ws = (char*)d_ws;
  const size_t MB16 = (size_t)16 * 1024 * 1024;
  unsigned short* xb = (unsigned short*)(ws);
  unsigned short* qb = (unsigned short*)(ws + 1 * MB16);
  unsigned short* kb = (unsigned short*)(ws + 2 * MB16);
  unsigned short* vb = (unsigned short*)(ws + 3 * MB16);
  unsigned short* ab = (unsigned short*)(ws + 4 * MB16);

  cvt_bf16_kernel<<<4096, 256, 0, stream>>>(x, xb);
  gemm_bf16<0><<<1024, 256, 0, stream>>>(xb, wq, qb, 0.125f);  // softmax scale folded
  gemm_bf16<0><<<1024, 256, 0, stream>>>(xb, wk, kb, 1.0f);
  gemm_bf16<0><<<1024, 256, 0, stream>>>(xb, wv, vb, 1.0f);
  attn_kernel<<<2048, 256, 0, stream>>>(qb, kb, vb, ab);
  gemm_bf16<1><<<1024, 256, 0, stream>>>(ab, wo, d_out, 1.0f);
}

// Round 11
// 1312.700 us; speedup vs baseline: 1.1736x; 1.1736x over previous
//
#include <hip/hip_runtime.h>

#define DIMN 8192
#define SEQ  1024
#define NHEAD 128

typedef __attribute__((ext_vector_type(8))) short bf16x8;
typedef __attribute__((ext_vector_type(4))) float f32x4;

#define MFMA16(a, b, c) __builtin_amdgcn_mfma_f32_16x16x32_bf16((a), (b), (c), 0, 0, 0)

__device__ __forceinline__ unsigned short f2bf(float f) {
  unsigned u = __float_as_uint(f);
  return (unsigned short)((u + 0x7FFFu + ((u >> 16) & 1u)) >> 16);
}
__device__ __forceinline__ unsigned pack2(float a, float b) {
  return (unsigned)f2bf(a) | ((unsigned)f2bf(b) << 16);
}
__device__ __forceinline__ unsigned pack2_rhu(float lo, float hi) {
  unsigned a = __float_as_uint(lo) + 0x8000u;
  unsigned b = __float_as_uint(hi) + 0x8000u;
  return (a >> 16) | (b & 0xFFFF0000u);
}
__device__ __forceinline__ void async_copy16(void* lds_dst, const void* gsrc) {
  __builtin_amdgcn_global_load_lds(
      (const __attribute__((address_space(1))) unsigned int*)gsrc,
      (__attribute__((address_space(3))) unsigned int*)lds_dst, 16, 0, 0);
}

// ---------------- fp32 -> bf16 convert (x) ----------------
__global__ __launch_bounds__(256) void cvt_bf16_kernel(
    const float* __restrict__ in, unsigned short* __restrict__ out) {
  int i = blockIdx.x * 256 + threadIdx.x;
  const float4* p = (const float4*)in;
  float4 a = p[2 * i];
  float4 b = p[2 * i + 1];
  uint4 r;
  r.x = pack2(a.x, a.y);
  r.y = pack2(a.z, a.w);
  r.z = pack2(b.x, b.y);
  r.w = pack2(b.z, b.w);
  ((uint4*)out)[i] = r;
}

// ---------------- GEMM: C[1024,8192] = A(bf16) @ W(f32->bf16) ----------------
// ROUND-10 SYNTHESIS: R5-R9 varied schedule at 8 waves/CU (277-310us); R10
// raised occupancy but broke the compute:staging ratio (404us, FETCH 2x).
// Untested axis: m97's exact recipe = per-wave 64x64 ratio AND 12 waves/CU of
// independent 4-wave blocks with a SIMPLE single-sync loop (874 TF reference;
// inter-block overlap per m114 absorbs the barrier drains).
// Config: 128x128 tile, BK=32, 256 thr (2x2 waves, 64x64 out each), 16 MFMA +
// 8 ds_read_b128 per wave-tile (m97 histogram), LDS dbuf 2x16KB=32KB ->
// launch_bounds(256,3) = 3 blocks/CU. A via global_load_lds (linear dest;
// BK=32 rows = 64B -> fragment reads conflict-free unswizzled: bank group
// 16(row&1)+4*slot). B: 16 scalar fp32 + pack_rhu + 2 ds_write_b128, slot
// swizzle p = s ^ ((n>>1)&3) (write & read sides both cover all 8 groups).
// BM=128 -> 8 m-sharers per W panel -> FETCH back to ~196MB. XCD swizzle:
// XCD x owns n-panels [8x,8x+8) with all 8 m-sharers co-resident.
template <int WRITE_F32>
__global__ __launch_bounds__(256, 3) void gemm_bf16(
    const unsigned short* __restrict__ A, const float* __restrict__ W,
    void* __restrict__ Cout, float out_scale) {
  __shared__ unsigned short smem[2 * 8192];  // per buf: A[128][32] + B_t[128][32]
  const int t = threadIdx.x;
  const int l = t & 63;
  const int w = t >> 6;                 // 0..3
  const int wm = w >> 1, wn = w & 1;    // 2x2 wave grid
  const int logical = (blockIdx.x & 7) * 64 + (blockIdx.x >> 3);  // XCD swizzle
  const int m0 = (logical & 7) * 128;
  const int n0 = (logical >> 3) * 128;

  // A staging: wave w stages rows [w*32, w*32+32); per instr 16 rows
  // (lane: row = l>>2, slot = l&3); dest linear (lane offset l*16B matches).
  const int arow = l >> 2;
  const int aslot = l & 3;
  // B staging: thread owns col bn, k-rows [bkb, bkb+16)
  const int bn = t & 127;
  const int bkb = (t >> 7) * 16;

  f32x4 acc[4][4];
#pragma unroll
  for (int mb = 0; mb < 4; ++mb)
#pragma unroll
    for (int nb = 0; nb < 4; ++nb) acc[mb][nb] = (f32x4){0.f, 0.f, 0.f, 0.f};

  float fb[16];
  const unsigned short* aptr = A + (size_t)(m0 + w * 32 + arow) * DIMN + aslot * 8;
  const float* wp = W + (size_t)bkb * DIMN + n0 + bn;

  auto load_B = [&]() {   // 16 coalesced scalar fp32 loads, advance k by 32
#pragma unroll
    for (int i = 0; i < 16; ++i) fb[i] = wp[(size_t)i * DIMN];
    wp += (size_t)32 * DIMN;
  };
  auto write_B = [&](int buf) {  // 2 ds_write_b128, conflict-free slot swizzle
    unsigned short* bb = &smem[buf * 8192 + 4096];
    const int ps = (bn >> 1) & 3;
#pragma unroll
    for (int j = 0; j < 2; ++j) {
      int p = ((bkb >> 3) + j) ^ ps;
      uint4 val;
      val.x = pack2_rhu(fb[j * 8 + 0], fb[j * 8 + 1]);
      val.y = pack2_rhu(fb[j * 8 + 2], fb[j * 8 + 3]);
      val.z = pack2_rhu(fb[j * 8 + 4], fb[j * 8 + 5]);
      val.w = pack2_rhu(fb[j * 8 + 6], fb[j * 8 + 7]);
      *(uint4*)&bb[bn * 32 + p * 8] = val;
    }
  };
  auto stage_A = [&](int buf) {  // 2 gload_lds per thread-wave, advance k by 32
#pragma unroll
    for (int i = 0; i < 2; ++i)
      async_copy16(&smem[buf * 8192 + (w * 32 + i * 16) * 32],
                   aptr + (size_t)i * 16 * DIMN);
    aptr += 32;
  };
  auto compute = [&](int buf) {  // 8 ds_read_b128 + 16 MFMA per wave
    const unsigned short* la = &smem[buf * 8192];
    const unsigned short* lb = la + 4096;
    bf16x8 af[4], bf[4];
#pragma unroll
    for (int mb = 0; mb < 4; ++mb) {
      int row = wm * 64 + mb * 16 + (l & 15);
      af[mb] = *(const bf16x8*)&la[row * 32 + (l >> 4) * 8];
    }
#pragma unroll
    for (int nb = 0; nb < 4; ++nb) {
      int row = wn * 64 + nb * 16 + (l & 15);
      int p = (l >> 4) ^ ((row >> 1) & 3);
      bf[nb] = *(const bf16x8*)&lb[row * 32 + p * 8];
    }
#pragma unroll
    for (int mb = 0; mb < 4; ++mb)
#pragma unroll
      for (int nb = 0; nb < 4; ++nb)
        acc[mb][nb] = MFMA16(af[mb], bf[nb], acc[mb][nb]);
  };

  // prologue: tile 0
  load_B();
  stage_A(0);
  write_B(0);
  __syncthreads();

  int buf = 0;
  for (int kt = 0; kt < 256; ++kt) {   // 256 K-tiles of 32
    if (kt < 255) {
      load_B();            // issue next-tile B fp32 loads (regs)
      stage_A(buf ^ 1);    // issue next-tile A DMA
    }
    compute(buf);
    if (kt < 255) write_B(buf ^ 1);
    __syncthreads();
    buf ^= 1;
  }

  // epilogue: D layout col=lane&15, row=(lane>>4)*4+reg (m89-verified)
#pragma unroll
  for (int mb = 0; mb < 4; ++mb)
#pragma unroll
    for (int nb = 0; nb < 4; ++nb)
#pragma unroll
      for (int r = 0; r < 4; ++r) {
        int rg = m0 + wm * 64 + mb * 16 + (l >> 4) * 4 + r;
        int cg = n0 + wn * 64 + nb * 16 + (l & 15);
        float vl = acc[mb][nb][r] * out_scale;
        if (WRITE_F32)
          ((float*)Cout)[(size_t)rg * DIMN + cg] = vl;
        else
          ((unsigned short*)Cout)[(size_t)rg * DIMN + cg] = f2bf(vl);
      }
}

// ---------------- fused flash attention (unchanged) ----------------
__global__ __launch_bounds__(256) void attn_kernel(
    const unsigned short* __restrict__ q, const unsigned short* __restrict__ k,
    const unsigned short* __restrict__ v, unsigned short* __restrict__ o) {
  __shared__ unsigned short Qs[64 * 72];
  __shared__ unsigned short Ks[64 * 72];
  __shared__ unsigned short Vt[64 * 72];
  __shared__ unsigned short Ps[4][16 * 72];

  const int t = threadIdx.x, l = t & 63, w = t >> 6;
  const int h = blockIdx.x >> 4;
  const int q0 = (blockIdx.x & 15) * 64;
  const int skey = t >> 2;
  const int sd = (t & 3) * 16;

  {
    const unsigned short* src = q + (size_t)(q0 + skey) * DIMN + h * 64 + sd;
    uint4 a = *(const uint4*)src;
    uint4 b = *(const uint4*)(src + 8);
    *(uint4*)&Qs[skey * 72 + sd] = a;
    *(uint4*)&Qs[skey * 72 + sd + 8] = b;
  }
  __syncthreads();
  bf16x8 qf[2];
#pragma unroll
  for (int kh = 0; kh < 2; ++kh)
    qf[kh] = *(const bf16x8*)&Qs[(w * 16 + (l & 15)) * 72 + (l >> 4) * 8 + kh * 32];

  float m_run[4] = {-1e30f, -1e30f, -1e30f, -1e30f};
  float l_run[4] = {0.f, 0.f, 0.f, 0.f};
  f32x4 oacc[4];
#pragma unroll
  for (int db = 0; db < 4; ++db) oacc[db] = (f32x4){0.f, 0.f, 0.f, 0.f};

  for (int kv = 0; kv < 16; ++kv) {
    __syncthreads();
    {
      const unsigned short* ksrc = k + (size_t)(kv * 64 + skey) * DIMN + h * 64 + sd;
      uint4 a = *(const uint4*)ksrc;
      uint4 b = *(const uint4*)(ksrc + 8);
      *(uint4*)&Ks[skey * 72 + sd] = a;
      *(uint4*)&Ks[skey * 72 + sd + 8] = b;
      const unsigned short* vsrc = v + (size_t)(kv * 64 + skey) * DIMN + h * 64 + sd;
      uint4 c = *(const uint4*)vsrc;
      uint4 d = *(const uint4*)(vsrc + 8);
      const unsigned short* cs = (const unsigned short*)&c;
      const unsigned short* ds = (const unsigned short*)&d;
#pragma unroll
      for (int j = 0; j < 8; ++j) Vt[(sd + j) * 72 + skey] = cs[j];
#pragma unroll
      for (int j = 0; j < 8; ++j) Vt[(sd + 8 + j) * 72 + skey] = ds[j];
    }
    __syncthreads();

    f32x4 sAcc[4];
#pragma unroll
    for (int nb = 0; nb < 4; ++nb) sAcc[nb] = (f32x4){0.f, 0.f, 0.f, 0.f};
#pragma unroll
    for (int kh = 0; kh < 2; ++kh) {
#pragma unroll
      for (int nb = 0; nb < 4; ++nb) {
        bf16x8 kf = *(const bf16x8*)&Ks[(nb * 16 + (l & 15)) * 72 + (l >> 4) * 8 + kh * 32];
        sAcc[nb] = MFMA16(qf[kh], kf, sAcc[nb]);
      }
    }

    float sc[4], mx[4];
#pragma unroll
    for (int r = 0; r < 4; ++r) {
      float mv = fmaxf(fmaxf(sAcc[0][r], sAcc[1][r]), fmaxf(sAcc[2][r], sAcc[3][r]));
      mv = fmaxf(mv, __shfl_xor(mv, 1));
      mv = fmaxf(mv, __shfl_xor(mv, 2));
      mv = fmaxf(mv, __shfl_xor(mv, 4));
      mv = fmaxf(mv, __shfl_xor(mv, 8));
      float mn = fmaxf(m_run[r], mv);
      sc[r] = __expf(m_run[r] - mn);
      m_run[r] = mn;
      mx[r] = mn;
    }
#pragma unroll
    for (int nb = 0; nb < 4; ++nb) {
      f32x4 sv = sAcc[nb];
#pragma unroll
      for (int r = 0; r < 4; ++r) sv[r] = __expf(sv[r] - mx[r]);
      sAcc[nb] = sv;
    }
#pragma unroll
    for (int r = 0; r < 4; ++r) {
      float ls = sAcc[0][r] + sAcc[1][r] + sAcc[2][r] + sAcc[3][r];
      ls += __shfl_xor(ls, 1);
      ls += __shfl_xor(ls, 2);
      ls += __shfl_xor(ls, 4);
      ls += __shfl_xor(ls, 8);
      l_run[r] = l_run[r] * sc[r] + ls;
    }
#pragma unroll
    for (int db = 0; db < 4; ++db) {
      f32x4 ov = oacc[db];
#pragma unroll
      for (int r = 0; r < 4; ++r) ov[r] *= sc[r];
      oacc[db] = ov;
    }

#pragma unroll
    for (int nb = 0; nb < 4; ++nb)
#pragma unroll
      for (int r = 0; r < 4; ++r)
        Ps[w][((l >> 4) * 4 + r) * 72 + nb * 16 + (l & 15)] = f2bf(sAcc[nb][r]);

#pragma unroll
    for (int kh = 0; kh < 2; ++kh) {
      bf16x8 pf = *(const bf16x8*)&Ps[w][(l & 15) * 72 + (l >> 4) * 8 + kh * 32];
#pragma unroll
      for (int db = 0; db < 4; ++db) {
        bf16x8 vf = *(const bf16x8*)&Vt[(db * 16 + (l & 15)) * 72 + (l >> 4) * 8 + kh * 32];
        oacc[db] = MFMA16(pf, vf, oacc[db]);
      }
    }
  }

#pragma unroll
  for (int db = 0; db < 4; ++db)
#pragma unroll
    for (int r = 0; r < 4; ++r) {
      float vl = oacc[db][r] / l_run[r];
      int rg = q0 + w * 16 + (l >> 4) * 4 + r;
      int cg = h * 64 + db * 16 + (l & 15);
      o[(size_t)rg * DIMN + cg] = f2bf(vl);
    }
}

extern "C" void kernel_launch(void* const* d_in, const int* in_sizes, int n_in,
                              void* d_out, int out_size, void* d_ws, size_t ws_size,
                              hipStream_t stream) {
  const float* x  = (const float*)d_in[0];
  const float* wq = (const float*)d_in[1];
  const float* wk = (const float*)d_in[2];
  const float* wv = (const float*)d_in[3];
  const float* wo = (const float*)d_in[4];

  char* ws = (char*)d_ws;
  const size_t MB16 = (size_t)16 * 1024 * 1024;
  unsigned short* xb = (unsigned short*)(ws);
  unsigned short* qb = (unsigned short*)(ws + 1 * MB16);
  unsigned short* kb = (unsigned short*)(ws + 2 * MB16);
  unsigned short* vb = (unsigned short*)(ws + 3 * MB16);
  unsigned short* ab = (unsigned short*)(ws + 4 * MB16);

  cvt_bf16_kernel<<<4096, 256, 0, stream>>>(x, xb);
  gemm_bf16<0><<<512, 256, 0, stream>>>(xb, wq, qb, 0.125f);  // softmax scale folded
  gemm_bf16<0><<<512, 256, 0, stream>>>(xb, wk, kb, 1.0f);
  gemm_bf16<0><<<512, 256, 0, stream>>>(xb, wv, vb, 1.0f);
  attn_kernel<<<2048, 256, 0, stream>>>(qb, kb, vb, ab);
  gemm_bf16<1><<<512, 256, 0, stream>>>(ab, wo, d_out, 1.0f);
}

// Round 12
// 1092.319 us; speedup vs baseline: 1.4104x; 1.2018x over previous
//
#include <hip/hip_runtime.h>

#define DIMN 8192
#define SEQ  1024
#define NHEAD 128

typedef __attribute__((ext_vector_type(8))) short bf16x8;
typedef __attribute__((ext_vector_type(4))) float f32x4;

#define MFMA16(a, b, c) __builtin_amdgcn_mfma_f32_16x16x32_bf16((a), (b), (c), 0, 0, 0)

__device__ __forceinline__ unsigned short f2bf(float f) {
  unsigned u = __float_as_uint(f);
  return (unsigned short)((u + 0x7FFFu + ((u >> 16) & 1u)) >> 16);
}
__device__ __forceinline__ unsigned pack2(float a, float b) {
  return (unsigned)f2bf(a) | ((unsigned)f2bf(b) << 16);
}
__device__ __forceinline__ unsigned pack2_rhu(float lo, float hi) {
  unsigned a = __float_as_uint(lo) + 0x8000u;
  unsigned b = __float_as_uint(hi) + 0x8000u;
  return (a >> 16) | (b & 0xFFFF0000u);
}
__device__ __forceinline__ unsigned short f2bf_rhu(float f) {
  return (unsigned short)((__float_as_uint(f) + 0x8000u) >> 16);
}
__device__ __forceinline__ void async_copy16(void* lds_dst, const void* gsrc) {
  __builtin_amdgcn_global_load_lds(
      (const __attribute__((address_space(1))) unsigned int*)gsrc,
      (__attribute__((address_space(3))) unsigned int*)lds_dst, 16, 0, 0);
}

// ---------------- fp32 -> bf16 convert (x) ----------------
__global__ __launch_bounds__(256) void cvt_bf16_kernel(
    const float* __restrict__ in, unsigned short* __restrict__ out) {
  int i = blockIdx.x * 256 + threadIdx.x;
  const float4* p = (const float4*)in;
  float4 a = p[2 * i];
  float4 b = p[2 * i + 1];
  uint4 r;
  r.x = pack2(a.x, a.y);
  r.y = pack2(a.z, a.w);
  r.z = pack2(b.x, b.y);
  r.w = pack2(b.z, b.w);
  ((uint4*)out)[i] = r;
}

// ------------- W[k][n] fp32 -> Wt[n][k] bf16 (tiled transpose+convert) -------------
// 64x64 tiles, 256 thr. Phase1: coalesced float4 reads, transposed scalar LDS
// writes (padded rows). Phase2: contiguous 32B LDS reads, coalesced 32B global
// writes. Row pad 72 shorts = 144B (multiple of 16 -> aligned uint4 reads).
__global__ __launch_bounds__(256) void transpose_cvt_kernel(
    const float* __restrict__ W, unsigned short* __restrict__ Wt) {
  __shared__ unsigned short T[64][72];
  const int t = threadIdx.x;
  const int k0 = (blockIdx.x & 127) * 64;
  const int n0 = (blockIdx.x >> 7) * 64;
  const int c4 = (t & 15) * 4;   // n-offset of this thread's float4
  const int kk = t >> 4;         // k-offset base (0..15)
#pragma unroll
  for (int i = 0; i < 4; ++i) {
    int k = kk + i * 16;
    float4 v = *(const float4*)&W[(size_t)(k0 + k) * DIMN + n0 + c4];
    T[c4 + 0][k] = f2bf_rhu(v.x);
    T[c4 + 1][k] = f2bf_rhu(v.y);
    T[c4 + 2][k] = f2bf_rhu(v.z);
    T[c4 + 3][k] = f2bf_rhu(v.w);
  }
  __syncthreads();
  const int r = t >> 2;          // n-row 0..63
  const int c = (t & 3) * 16;    // k-chunk
  const uint4* src = (const uint4*)&T[r][c];
  uint4* dst = (uint4*)&Wt[(size_t)(n0 + r) * DIMN + k0 + c];
  dst[0] = src[0];
  dst[1] = src[1];
}

// ---------------- pure-DMA GEMM: C[1024,8192] = A(bf16) @ Wt^T (bf16) ----------------
// ROUND-11 SYNTHESIS: the invariant across R2-R11 (~280-330us, all pipes <30%)
// is the per-tile fp32 B-staging stream (32 scalar VMEM + ~20 pack VALU + 4
// ds_write per thread per tile). m97 (874 TF, this exact structure) has NONE:
// both operands arrive via global_load_lds. With Wt[n][k] bf16 precomputed,
// B-staging becomes identical to the verified A-staging: 4 gload_lds per wave.
// 128x128 tile, BK=64, 256 thr (2x2 waves, 64x64 out), dbuf LDS 64KB -> 2
// blocks/CU (= grid cap 512/256). Per wave per tile: 8 DMA + 16 ds_read_b128 +
// 32 MFMA — no staging VALU at all. Fragment reads: R6 pattern (measured 0
// conflicts). Wt freshly written -> L3-warm -> FETCH should collapse.
// XCD swizzle: bijective, XCD x owns n-panels [8x,8x+8) with all 8 m-sharers.
template <int WRITE_F32>
__global__ __launch_bounds__(256, 2) void gemm_dma(
    const unsigned short* __restrict__ A, const unsigned short* __restrict__ Wt,
    void* __restrict__ Cout, float out_scale) {
  __shared__ unsigned short smem[2 * 16384];  // per buf: A[128][64] + Bt[128][64]
  const int t = threadIdx.x;
  const int l = t & 63;
  const int w = t >> 6;
  const int wm = w >> 1, wn = w & 1;
  const int logical = (blockIdx.x & 7) * 64 + (blockIdx.x >> 3);
  const int m0 = (logical & 7) * 128;
  const int n0 = (logical >> 3) * 128;

  // staging geometry (R1-verified): one gload_lds = 8 rows x 8 slots(16B);
  // source slot pre-swizzled so LDS[row][p] = source slot p ^ (row&7).
  const int rin = l >> 3;
  const int aslot = (l & 7) ^ rin;

  f32x4 acc[4][4];
#pragma unroll
  for (int mb = 0; mb < 4; ++mb)
#pragma unroll
    for (int nb = 0; nb < 4; ++nb) acc[mb][nb] = (f32x4){0.f, 0.f, 0.f, 0.f};

  const unsigned short* aptr = A  + (size_t)(m0 + w * 32 + rin) * DIMN + aslot * 8;
  const unsigned short* bptr = Wt + (size_t)(n0 + w * 32 + rin) * DIMN + aslot * 8;

  auto stage = [&](int buf) {  // 8 gload_lds per wave (4 A + 4 B), advance k by 64
    unsigned short* sa = &smem[buf * 16384];
    unsigned short* sb = sa + 8192;
#pragma unroll
    for (int i = 0; i < 4; ++i)
      async_copy16(&sa[(w * 32 + i * 8) * 64], aptr + (size_t)i * 8 * DIMN);
#pragma unroll
    for (int i = 0; i < 4; ++i)
      async_copy16(&sb[(w * 32 + i * 8) * 64], bptr + (size_t)i * 8 * DIMN);
    aptr += 64;
    bptr += 64;
  };
  auto compute = [&](int buf) {
    const unsigned short* la = &smem[buf * 16384];
    const unsigned short* lb = la + 8192;
#pragma unroll
    for (int kh = 0; kh < 2; ++kh) {
      bf16x8 af[4], bf[4];
#pragma unroll
      for (int mb = 0; mb < 4; ++mb) {
        int row = wm * 64 + mb * 16 + (l & 15);
        int sl = ((l >> 4) + kh * 4) ^ (row & 7);
        af[mb] = *(const bf16x8*)&la[row * 64 + sl * 8];
      }
#pragma unroll
      for (int nb = 0; nb < 4; ++nb) {
        int row = wn * 64 + nb * 16 + (l & 15);
        int sl = ((l >> 4) + kh * 4) ^ (row & 7);
        bf[nb] = *(const bf16x8*)&lb[row * 64 + sl * 8];
      }
      __builtin_amdgcn_s_setprio(1);
#pragma unroll
      for (int mb = 0; mb < 4; ++mb)
#pragma unroll
        for (int nb = 0; nb < 4; ++nb)
          acc[mb][nb] = MFMA16(af[mb], bf[nb], acc[mb][nb]);
      __builtin_amdgcn_s_setprio(0);
    }
  };

  stage(0);
  __syncthreads();
  int buf = 0;
  for (int kt = 0; kt < 128; ++kt) {
    if (kt < 127) stage(buf ^ 1);
    compute(buf);
    __syncthreads();
    buf ^= 1;
  }

  // epilogue: D layout col=lane&15, row=(lane>>4)*4+reg (m89-verified)
#pragma unroll
  for (int mb = 0; mb < 4; ++mb)
#pragma unroll
    for (int nb = 0; nb < 4; ++nb)
#pragma unroll
      for (int r = 0; r < 4; ++r) {
        int rg = m0 + wm * 64 + mb * 16 + (l >> 4) * 4 + r;
        int cg = n0 + wn * 64 + nb * 16 + (l & 15);
        float vl = acc[mb][nb][r] * out_scale;
        if (WRITE_F32)
          ((float*)Cout)[(size_t)rg * DIMN + cg] = vl;
        else
          ((unsigned short*)Cout)[(size_t)rg * DIMN + cg] = f2bf(vl);
      }
}

// ---------------- fallback GEMM (R11, fp32-W reg-staging) — used only if ws too small ----
template <int WRITE_F32>
__global__ __launch_bounds__(256, 3) void gemm_fb(
    const unsigned short* __restrict__ A, const float* __restrict__ W,
    void* __restrict__ Cout, float out_scale) {
  __shared__ unsigned short smem[2 * 8192];
  const int t = threadIdx.x;
  const int l = t & 63;
  const int w = t >> 6;
  const int wm = w >> 1, wn = w & 1;
  const int logical = (blockIdx.x & 7) * 64 + (blockIdx.x >> 3);
  const int m0 = (logical & 7) * 128;
  const int n0 = (logical >> 3) * 128;
  const int arow = l >> 2;
  const int aslot = l & 3;
  const int bn = t & 127;
  const int bkb = (t >> 7) * 16;

  f32x4 acc[4][4];
#pragma unroll
  for (int mb = 0; mb < 4; ++mb)
#pragma unroll
    for (int nb = 0; nb < 4; ++nb) acc[mb][nb] = (f32x4){0.f, 0.f, 0.f, 0.f};

  float fb[16];
  const unsigned short* aptr = A + (size_t)(m0 + w * 32 + arow) * DIMN + aslot * 8;
  const float* wp = W + (size_t)bkb * DIMN + n0 + bn;

  auto load_B = [&]() {
#pragma unroll
    for (int i = 0; i < 16; ++i) fb[i] = wp[(size_t)i * DIMN];
    wp += (size_t)32 * DIMN;
  };
  auto write_B = [&](int buf) {
    unsigned short* bb = &smem[buf * 8192 + 4096];
    const int ps = (bn >> 1) & 3;
#pragma unroll
    for (int j = 0; j < 2; ++j) {
      int p = ((bkb >> 3) + j) ^ ps;
      uint4 val;
      val.x = pack2_rhu(fb[j * 8 + 0], fb[j * 8 + 1]);
      val.y = pack2_rhu(fb[j * 8 + 2], fb[j * 8 + 3]);
      val.z = pack2_rhu(fb[j * 8 + 4], fb[j * 8 + 5]);
      val.w = pack2_rhu(fb[j * 8 + 6], fb[j * 8 + 7]);
      *(uint4*)&bb[bn * 32 + p * 8] = val;
    }
  };
  auto stage_A = [&](int buf) {
#pragma unroll
    for (int i = 0; i < 2; ++i)
      async_copy16(&smem[buf * 8192 + (w * 32 + i * 16) * 32],
                   aptr + (size_t)i * 16 * DIMN);
    aptr += 32;
  };
  auto compute = [&](int buf) {
    const unsigned short* la = &smem[buf * 8192];
    const unsigned short* lb = la + 4096;
    bf16x8 af[4], bf[4];
#pragma unroll
    for (int mb = 0; mb < 4; ++mb) {
      int row = wm * 64 + mb * 16 + (l & 15);
      af[mb] = *(const bf16x8*)&la[row * 32 + (l >> 4) * 8];
    }
#pragma unroll
    for (int nb = 0; nb < 4; ++nb) {
      int row = wn * 64 + nb * 16 + (l & 15);
      int p = (l >> 4) ^ ((row >> 1) & 3);
      bf[nb] = *(const bf16x8*)&lb[row * 32 + p * 8];
    }
#pragma unroll
    for (int mb = 0; mb < 4; ++mb)
#pragma unroll
      for (int nb = 0; nb < 4; ++nb)
        acc[mb][nb] = MFMA16(af[mb], bf[nb], acc[mb][nb]);
  };

  load_B();
  stage_A(0);
  write_B(0);
  __syncthreads();
  int buf = 0;
  for (int kt = 0; kt < 256; ++kt) {
    if (kt < 255) {
      load_B();
      stage_A(buf ^ 1);
    }
    compute(buf);
    if (kt < 255) write_B(buf ^ 1);
    __syncthreads();
    buf ^= 1;
  }
#pragma unroll
  for (int mb = 0; mb < 4; ++mb)
#pragma unroll
    for (int nb = 0; nb < 4; ++nb)
#pragma unroll
      for (int r = 0; r < 4; ++r) {
        int rg = m0 + wm * 64 + mb * 16 + (l >> 4) * 4 + r;
        int cg = n0 + wn * 64 + nb * 16 + (l & 15);
        float vl = acc[mb][nb][r] * out_scale;
        if (WRITE_F32)
          ((float*)Cout)[(size_t)rg * DIMN + cg] = vl;
        else
          ((unsigned short*)Cout)[(size_t)rg * DIMN + cg] = f2bf(vl);
      }
}

// ---------------- fused flash attention (unchanged) ----------------
__global__ __launch_bounds__(256) void attn_kernel(
    const unsigned short* __restrict__ q, const unsigned short* __restrict__ k,
    const unsigned short* __restrict__ v, unsigned short* __restrict__ o) {
  __shared__ unsigned short Qs[64 * 72];
  __shared__ unsigned short Ks[64 * 72];
  __shared__ unsigned short Vt[64 * 72];
  __shared__ unsigned short Ps[4][16 * 72];

  const int t = threadIdx.x, l = t & 63, w = t >> 6;
  const int h = blockIdx.x >> 4;
  const int q0 = (blockIdx.x & 15) * 64;
  const int skey = t >> 2;
  const int sd = (t & 3) * 16;

  {
    const unsigned short* src = q + (size_t)(q0 + skey) * DIMN + h * 64 + sd;
    uint4 a = *(const uint4*)src;
    uint4 b = *(const uint4*)(src + 8);
    *(uint4*)&Qs[skey * 72 + sd] = a;
    *(uint4*)&Qs[skey * 72 + sd + 8] = b;
  }
  __syncthreads();
  bf16x8 qf[2];
#pragma unroll
  for (int kh = 0; kh < 2; ++kh)
    qf[kh] = *(const bf16x8*)&Qs[(w * 16 + (l & 15)) * 72 + (l >> 4) * 8 + kh * 32];

  float m_run[4] = {-1e30f, -1e30f, -1e30f, -1e30f};
  float l_run[4] = {0.f, 0.f, 0.f, 0.f};
  f32x4 oacc[4];
#pragma unroll
  for (int db = 0; db < 4; ++db) oacc[db] = (f32x4){0.f, 0.f, 0.f, 0.f};

  for (int kv = 0; kv < 16; ++kv) {
    __syncthreads();
    {
      const unsigned short* ksrc = k + (size_t)(kv * 64 + skey) * DIMN + h * 64 + sd;
      uint4 a = *(const uint4*)ksrc;
      uint4 b = *(const uint4*)(ksrc + 8);
      *(uint4*)&Ks[skey * 72 + sd] = a;
      *(uint4*)&Ks[skey * 72 + sd + 8] = b;
      const unsigned short* vsrc = v + (size_t)(kv * 64 + skey) * DIMN + h * 64 + sd;
      uint4 c = *(const uint4*)vsrc;
      uint4 d = *(const uint4*)(vsrc + 8);
      const unsigned short* cs = (const unsigned short*)&c;
      const unsigned short* ds = (const unsigned short*)&d;
#pragma unroll
      for (int j = 0; j < 8; ++j) Vt[(sd + j) * 72 + skey] = cs[j];
#pragma unroll
      for (int j = 0; j < 8; ++j) Vt[(sd + 8 + j) * 72 + skey] = ds[j];
    }
    __syncthreads();

    f32x4 sAcc[4];
#pragma unroll
    for (int nb = 0; nb < 4; ++nb) sAcc[nb] = (f32x4){0.f, 0.f, 0.f, 0.f};
#pragma unroll
    for (int kh = 0; kh < 2; ++kh) {
#pragma unroll
      for (int nb = 0; nb < 4; ++nb) {
        bf16x8 kf = *(const bf16x8*)&Ks[(nb * 16 + (l & 15)) * 72 + (l >> 4) * 8 + kh * 32];
        sAcc[nb] = MFMA16(qf[kh], kf, sAcc[nb]);
      }
    }

    float sc[4], mx[4];
#pragma unroll
    for (int r = 0; r < 4; ++r) {
      float mv = fmaxf(fmaxf(sAcc[0][r], sAcc[1][r]), fmaxf(sAcc[2][r], sAcc[3][r]));
      mv = fmaxf(mv, __shfl_xor(mv, 1));
      mv = fmaxf(mv, __shfl_xor(mv, 2));
      mv = fmaxf(mv, __shfl_xor(mv, 4));
      mv = fmaxf(mv, __shfl_xor(mv, 8));
      float mn = fmaxf(m_run[r], mv);
      sc[r] = __expf(m_run[r] - mn);
      m_run[r] = mn;
      mx[r] = mn;
    }
#pragma unroll
    for (int nb = 0; nb < 4; ++nb) {
      f32x4 sv = sAcc[nb];
#pragma unroll
      for (int r = 0; r < 4; ++r) sv[r] = __expf(sv[r] - mx[r]);
      sAcc[nb] = sv;
    }
#pragma unroll
    for (int r = 0; r < 4; ++r) {
      float ls = sAcc[0][r] + sAcc[1][r] + sAcc[2][r] + sAcc[3][r];
      ls += __shfl_xor(ls, 1);
      ls += __shfl_xor(ls, 2);
      ls += __shfl_xor(ls, 4);
      ls += __shfl_xor(ls, 8);
      l_run[r] = l_run[r] * sc[r] + ls;
    }
#pragma unroll
    for (int db = 0; db < 4; ++db) {
      f32x4 ov = oacc[db];
#pragma unroll
      for (int r = 0; r < 4; ++r) ov[r] *= sc[r];
      oacc[db] = ov;
    }

#pragma unroll
    for (int nb = 0; nb < 4; ++nb)
#pragma unroll
      for (int r = 0; r < 4; ++r)
        Ps[w][((l >> 4) * 4 + r) * 72 + nb * 16 + (l & 15)] = f2bf(sAcc[nb][r]);

#pragma unroll
    for (int kh = 0; kh < 2; ++kh) {
      bf16x8 pf = *(const bf16x8*)&Ps[w][(l & 15) * 72 + (l >> 4) * 8 + kh * 32];
#pragma unroll
      for (int db = 0; db < 4; ++db) {
        bf16x8 vf = *(const bf16x8*)&Vt[(db * 16 + (l & 15)) * 72 + (l >> 4) * 8 + kh * 32];
        oacc[db] = MFMA16(pf, vf, oacc[db]);
      }
    }
  }

#pragma unroll
  for (int db = 0; db < 4; ++db)
#pragma unroll
    for (int r = 0; r < 4; ++r) {
      float vl = oacc[db][r] / l_run[r];
      int rg = q0 + w * 16 + (l >> 4) * 4 + r;
      int cg = h * 64 + db * 16 + (l & 15);
      o[(size_t)rg * DIMN + cg] = f2bf(vl);
    }
}

extern "C" void kernel_launch(void* const* d_in, const int* in_sizes, int n_in,
                              void* d_out, int out_size, void* d_ws, size_t ws_size,
                              hipStream_t stream) {
  const float* x  = (const float*)d_in[0];
  const float* wq = (const float*)d_in[1];
  const float* wk = (const float*)d_in[2];
  const float* wv = (const float*)d_in[3];
  const float* wo = (const float*)d_in[4];

  char* ws = (char*)d_ws;
  const size_t MB16 = (size_t)16 * 1024 * 1024;
  unsigned short* xb = (unsigned short*)(ws);
  unsigned short* qb = (unsigned short*)(ws + 1 * MB16);
  unsigned short* kb = (unsigned short*)(ws + 2 * MB16);
  unsigned short* vb = (unsigned short*)(ws + 3 * MB16);
  unsigned short* ab = (unsigned short*)(ws + 4 * MB16);
  unsigned short* Wt = (unsigned short*)(ws + 5 * MB16);  // 128 MB, reused serially

  const size_t WT_BYTES = (size_t)DIMN * DIMN * 2;        // 134217728
  const size_t NEEDED = 5 * MB16 + WT_BYTES;              // ~208 MB

  cvt_bf16_kernel<<<4096, 256, 0, stream>>>(x, xb);

  if (ws_size >= NEEDED) {
    // pure-DMA path: transpose+convert each W into the shared Wt buffer,
    // run the DMA GEMM while Wt is L3-warm, then overwrite for the next.
    transpose_cvt_kernel<<<16384, 256, 0, stream>>>(wq, Wt);
    gemm_dma<0><<<512, 256, 0, stream>>>(xb, Wt, qb, 0.125f);  // softmax scale folded
    transpose_cvt_kernel<<<16384, 256, 0, stream>>>(wk, Wt);
    gemm_dma<0><<<512, 256, 0, stream>>>(xb, Wt, kb, 1.0f);
    transpose_cvt_kernel<<<16384, 256, 0, stream>>>(wv, Wt);
    gemm_dma<0><<<512, 256, 0, stream>>>(xb, Wt, vb, 1.0f);
    attn_kernel<<<2048, 256, 0, stream>>>(qb, kb, vb, ab);
    transpose_cvt_kernel<<<16384, 256, 0, stream>>>(wo, Wt);
    gemm_dma<1><<<512, 256, 0, stream>>>(ab, Wt, d_out, 1.0f);
  } else {
    // fallback: R11 reg-staging path (verified passing)
    gemm_fb<0><<<512, 256, 0, stream>>>(xb, wq, qb, 0.125f);
    gemm_fb<0><<<512, 256, 0, stream>>>(xb, wk, kb, 1.0f);
    gemm_fb<0><<<512, 256, 0, stream>>>(xb, wv, vb, 1.0f);
    attn_kernel<<<2048, 256, 0, stream>>>(qb, kb, vb, ab);
    gemm_fb<1><<<512, 256, 0, stream>>>(ab, wo, d_out, 1.0f);
  }
}

// Round 13
// 1071.035 us; speedup vs baseline: 1.4384x; 1.0199x over previous
//
#include <hip/hip_runtime.h>

#define DIMN 8192
#define SEQ  1024
#define NHEAD 128

typedef __attribute__((ext_vector_type(8))) short bf16x8;
typedef __attribute__((ext_vector_type(4))) float f32x4;

#define MFMA16(a, b, c) __builtin_amdgcn_mfma_f32_16x16x32_bf16((a), (b), (c), 0, 0, 0)

__device__ __forceinline__ unsigned short f2bf(float f) {
  unsigned u = __float_as_uint(f);
  return (unsigned short)((u + 0x7FFFu + ((u >> 16) & 1u)) >> 16);
}
__device__ __forceinline__ unsigned pack2(float a, float b) {
  return (unsigned)f2bf(a) | ((unsigned)f2bf(b) << 16);
}
__device__ __forceinline__ unsigned pack2_rhu(float lo, float hi) {
  unsigned a = __float_as_uint(lo) + 0x8000u;
  unsigned b = __float_as_uint(hi) + 0x8000u;
  return (a >> 16) | (b & 0xFFFF0000u);
}
__device__ __forceinline__ unsigned short f2bf_rhu(float f) {
  return (unsigned short)((__float_as_uint(f) + 0x8000u) >> 16);
}
__device__ __forceinline__ void async_copy16(void* lds_dst, const void* gsrc) {
  __builtin_amdgcn_global_load_lds(
      (const __attribute__((address_space(1))) unsigned int*)gsrc,
      (__attribute__((address_space(3))) unsigned int*)lds_dst, 16, 0, 0);
}

// ---------------- fp32 -> bf16 convert (x) ----------------
__global__ __launch_bounds__(256) void cvt_bf16_kernel(
    const float* __restrict__ in, unsigned short* __restrict__ out) {
  int i = blockIdx.x * 256 + threadIdx.x;
  const float4* p = (const float4*)in;
  float4 a = p[2 * i];
  float4 b = p[2 * i + 1];
  uint4 r;
  r.x = pack2(a.x, a.y);
  r.y = pack2(a.z, a.w);
  r.z = pack2(b.x, b.y);
  r.w = pack2(b.z, b.w);
  ((uint4*)out)[i] = r;
}

// ------------- W[k][n] fp32 -> Wt[n][k] bf16 (tiled transpose+convert) -------------
__global__ __launch_bounds__(256) void transpose_cvt_kernel(
    const float* __restrict__ W, unsigned short* __restrict__ Wt) {
  __shared__ unsigned short T[64][72];
  const int t = threadIdx.x;
  const int k0 = (blockIdx.x & 127) * 64;
  const int n0 = (blockIdx.x >> 7) * 64;
  const int c4 = (t & 15) * 4;
  const int kk = t >> 4;
#pragma unroll
  for (int i = 0; i < 4; ++i) {
    int k = kk + i * 16;
    float4 v = *(const float4*)&W[(size_t)(k0 + k) * DIMN + n0 + c4];
    T[c4 + 0][k] = f2bf_rhu(v.x);
    T[c4 + 1][k] = f2bf_rhu(v.y);
    T[c4 + 2][k] = f2bf_rhu(v.z);
    T[c4 + 3][k] = f2bf_rhu(v.w);
  }
  __syncthreads();
  const int r = t >> 2;
  const int c = (t & 3) * 16;
  const uint4* src = (const uint4*)&T[r][c];
  uint4* dst = (uint4*)&Wt[(size_t)(n0 + r) * DIMN + k0 + c];
  dst[0] = src[0];
  dst[1] = src[1];
}

// ---------------- pure-DMA GEMM (unchanged from R12, ~150us, ~900 TF) ----------------
template <int WRITE_F32>
__global__ __launch_bounds__(256, 2) void gemm_dma(
    const unsigned short* __restrict__ A, const unsigned short* __restrict__ Wt,
    void* __restrict__ Cout, float out_scale) {
  __shared__ unsigned short smem[2 * 16384];
  const int t = threadIdx.x;
  const int l = t & 63;
  const int w = t >> 6;
  const int wm = w >> 1, wn = w & 1;
  const int logical = (blockIdx.x & 7) * 64 + (blockIdx.x >> 3);
  const int m0 = (logical & 7) * 128;
  const int n0 = (logical >> 3) * 128;

  const int rin = l >> 3;
  const int aslot = (l & 7) ^ rin;

  f32x4 acc[4][4];
#pragma unroll
  for (int mb = 0; mb < 4; ++mb)
#pragma unroll
    for (int nb = 0; nb < 4; ++nb) acc[mb][nb] = (f32x4){0.f, 0.f, 0.f, 0.f};

  const unsigned short* aptr = A  + (size_t)(m0 + w * 32 + rin) * DIMN + aslot * 8;
  const unsigned short* bptr = Wt + (size_t)(n0 + w * 32 + rin) * DIMN + aslot * 8;

  auto stage = [&](int buf) {
    unsigned short* sa = &smem[buf * 16384];
    unsigned short* sb = sa + 8192;
#pragma unroll
    for (int i = 0; i < 4; ++i)
      async_copy16(&sa[(w * 32 + i * 8) * 64], aptr + (size_t)i * 8 * DIMN);
#pragma unroll
    for (int i = 0; i < 4; ++i)
      async_copy16(&sb[(w * 32 + i * 8) * 64], bptr + (size_t)i * 8 * DIMN);
    aptr += 64;
    bptr += 64;
  };
  auto compute = [&](int buf) {
    const unsigned short* la = &smem[buf * 16384];
    const unsigned short* lb = la + 8192;
#pragma unroll
    for (int kh = 0; kh < 2; ++kh) {
      bf16x8 af[4], bf[4];
#pragma unroll
      for (int mb = 0; mb < 4; ++mb) {
        int row = wm * 64 + mb * 16 + (l & 15);
        int sl = ((l >> 4) + kh * 4) ^ (row & 7);
        af[mb] = *(const bf16x8*)&la[row * 64 + sl * 8];
      }
#pragma unroll
      for (int nb = 0; nb < 4; ++nb) {
        int row = wn * 64 + nb * 16 + (l & 15);
        int sl = ((l >> 4) + kh * 4) ^ (row & 7);
        bf[nb] = *(const bf16x8*)&lb[row * 64 + sl * 8];
      }
      __builtin_amdgcn_s_setprio(1);
#pragma unroll
      for (int mb = 0; mb < 4; ++mb)
#pragma unroll
        for (int nb = 0; nb < 4; ++nb)
          acc[mb][nb] = MFMA16(af[mb], bf[nb], acc[mb][nb]);
      __builtin_amdgcn_s_setprio(0);
    }
  };

  stage(0);
  __syncthreads();
  int buf = 0;
  for (int kt = 0; kt < 128; ++kt) {
    if (kt < 127) stage(buf ^ 1);
    compute(buf);
    __syncthreads();
    buf ^= 1;
  }

#pragma unroll
  for (int mb = 0; mb < 4; ++mb)
#pragma unroll
    for (int nb = 0; nb < 4; ++nb)
#pragma unroll
      for (int r = 0; r < 4; ++r) {
        int rg = m0 + wm * 64 + mb * 16 + (l >> 4) * 4 + r;
        int cg = n0 + wn * 64 + nb * 16 + (l & 15);
        float vl = acc[mb][nb][r] * out_scale;
        if (WRITE_F32)
          ((float*)Cout)[(size_t)rg * DIMN + cg] = vl;
        else
          ((unsigned short*)Cout)[(size_t)rg * DIMN + cg] = f2bf(vl);
      }
}

// ---------------- fallback GEMM (R11 reg-staging) — used only if ws too small ----
template <int WRITE_F32>
__global__ __launch_bounds__(256, 3) void gemm_fb(
    const unsigned short* __restrict__ A, const float* __restrict__ W,
    void* __restrict__ Cout, float out_scale) {
  __shared__ unsigned short smem[2 * 8192];
  const int t = threadIdx.x;
  const int l = t & 63;
  const int w = t >> 6;
  const int wm = w >> 1, wn = w & 1;
  const int logical = (blockIdx.x & 7) * 64 + (blockIdx.x >> 3);
  const int m0 = (logical & 7) * 128;
  const int n0 = (logical >> 3) * 128;
  const int arow = l >> 2;
  const int aslot = l & 3;
  const int bn = t & 127;
  const int bkb = (t >> 7) * 16;

  f32x4 acc[4][4];
#pragma unroll
  for (int mb = 0; mb < 4; ++mb)
#pragma unroll
    for (int nb = 0; nb < 4; ++nb) acc[mb][nb] = (f32x4){0.f, 0.f, 0.f, 0.f};

  float fb[16];
  const unsigned short* aptr = A + (size_t)(m0 + w * 32 + arow) * DIMN + aslot * 8;
  const float* wp = W + (size_t)bkb * DIMN + n0 + bn;

  auto load_B = [&]() {
#pragma unroll
    for (int i = 0; i < 16; ++i) fb[i] = wp[(size_t)i * DIMN];
    wp += (size_t)32 * DIMN;
  };
  auto write_B = [&](int buf) {
    unsigned short* bb = &smem[buf * 8192 + 4096];
    const int ps = (bn >> 1) & 3;
#pragma unroll
    for (int j = 0; j < 2; ++j) {
      int p = ((bkb >> 3) + j) ^ ps;
      uint4 val;
      val.x = pack2_rhu(fb[j * 8 + 0], fb[j * 8 + 1]);
      val.y = pack2_rhu(fb[j * 8 + 2], fb[j * 8 + 3]);
      val.z = pack2_rhu(fb[j * 8 + 4], fb[j * 8 + 5]);
      val.w = pack2_rhu(fb[j * 8 + 6], fb[j * 8 + 7]);
      *(uint4*)&bb[bn * 32 + p * 8] = val;
    }
  };
  auto stage_A = [&](int buf) {
#pragma unroll
    for (int i = 0; i < 2; ++i)
      async_copy16(&smem[buf * 8192 + (w * 32 + i * 16) * 32],
                   aptr + (size_t)i * 16 * DIMN);
    aptr += 32;
  };
  auto compute = [&](int buf) {
    const unsigned short* la = &smem[buf * 8192];
    const unsigned short* lb = la + 4096;
    bf16x8 af[4], bf[4];
#pragma unroll
    for (int mb = 0; mb < 4; ++mb) {
      int row = wm * 64 + mb * 16 + (l & 15);
      af[mb] = *(const bf16x8*)&la[row * 32 + (l >> 4) * 8];
    }
#pragma unroll
    for (int nb = 0; nb < 4; ++nb) {
      int row = wn * 64 + nb * 16 + (l & 15);
      int p = (l >> 4) ^ ((row >> 1) & 3);
      bf[nb] = *(const bf16x8*)&lb[row * 32 + p * 8];
    }
#pragma unroll
    for (int mb = 0; mb < 4; ++mb)
#pragma unroll
      for (int nb = 0; nb < 4; ++nb)
        acc[mb][nb] = MFMA16(af[mb], bf[nb], acc[mb][nb]);
  };

  load_B();
  stage_A(0);
  write_B(0);
  __syncthreads();
  int buf = 0;
  for (int kt = 0; kt < 256; ++kt) {
    if (kt < 255) {
      load_B();
      stage_A(buf ^ 1);
    }
    compute(buf);
    if (kt < 255) write_B(buf ^ 1);
    __syncthreads();
    buf ^= 1;
  }
#pragma unroll
  for (int mb = 0; mb < 4; ++mb)
#pragma unroll
    for (int nb = 0; nb < 4; ++nb)
#pragma unroll
      for (int r = 0; r < 4; ++r) {
        int rg = m0 + wm * 64 + mb * 16 + (l >> 4) * 4 + r;
        int cg = n0 + wn * 64 + nb * 16 + (l & 15);
        float vl = acc[mb][nb][r] * out_scale;
        if (WRITE_F32)
          ((float*)Cout)[(size_t)rg * DIMN + cg] = vl;
        else
          ((unsigned short*)Cout)[(size_t)rg * DIMN + cg] = f2bf(vl);
      }
}

// ---------------- fused flash attention v2 ----------------
// R12 DIAGNOSIS: 22M bank conflicts (8-way on transposed-V scalar writes +
// K/Q uint4 staging), per-tile exposed K/V load latency, RNE pack VALU.
// FIXES: K,Q staged via global_load_lds (0 write conflicts; R1-verified slot
// swizzle for reads); K double-buffered so its DMA hides under compute;
// V reg-prefetch (T14: loads for t+1 issued at top of compute region);
// Vt chunk-XOR swizzle phys=(skey>>3)^((row>>3)&7) (writes conflict-free,
// PV reads 2-way=free); f2bf_rhu for P; setprio around MFMA; XCD swizzle
// groups each head's 16 blocks on one XCD (K/V set 4MB = L2).
// LDS: Qs 8K + Ks 2x8K + Vt 9K + Ps 9K = 43KB -> 3 blocks/CU.
__global__ __launch_bounds__(256) void attn_kernel(
    const unsigned short* __restrict__ q, const unsigned short* __restrict__ k,
    const unsigned short* __restrict__ v, unsigned short* __restrict__ o) {
  __shared__ unsigned short Qs[64 * 64];
  __shared__ unsigned short Ks[2][64 * 64];
  __shared__ unsigned short Vt[64 * 72];
  __shared__ unsigned short Ps[4][16 * 72];

  const int t = threadIdx.x, l = t & 63, w = t >> 6;
  const int logical = (blockIdx.x & 7) * 256 + (blockIdx.x >> 3);  // XCD swizzle
  const int h = logical >> 4;
  const int q0 = (logical & 15) * 64;

  const int rin = l >> 3;                // DMA: row-in-group
  const int aslot = (l & 7) ^ rin;       // pre-swizzled source slot
  const int skey = t >> 2;               // V staging: key row 0..63
  const int sd = (t & 3) * 16;           // V staging: d base

  const unsigned short* qsrc = q + (size_t)(q0 + w * 16 + rin) * DIMN + h * 64 + aslot * 8;
  const unsigned short* ksrc = k + (size_t)(w * 16 + rin) * DIMN + h * 64 + aslot * 8;
  const unsigned short* vsrc = v + (size_t)skey * DIMN + h * 64 + sd;

  auto kdma = [&](int buf, int kv) {
#pragma unroll
    for (int i = 0; i < 2; ++i)
      async_copy16(&Ks[buf][(w * 16 + i * 8) * 64],
                   ksrc + (size_t)(kv * 64 + i * 8) * DIMN);
  };
  uint4 va0, va1, vb0, vb1;
  auto vload = [&](uint4& r0, uint4& r1, int kv) {
    const unsigned short* p = vsrc + (size_t)(kv * 64) * DIMN;
    r0 = *(const uint4*)p;
    r1 = *(const uint4*)(p + 8);
  };
  auto vwrite = [&](const uint4& r0, const uint4& r1) {
    const unsigned short* cs = (const unsigned short*)&r0;
    const unsigned short* ds = (const unsigned short*)&r1;
#pragma unroll
    for (int j = 0; j < 8; ++j) {
      int row = sd + j;
      Vt[row * 72 + (((skey >> 3) ^ ((row >> 3) & 7)) << 3) + (skey & 7)] = cs[j];
    }
#pragma unroll
    for (int j = 0; j < 8; ++j) {
      int row = sd + 8 + j;
      Vt[row * 72 + (((skey >> 3) ^ ((row >> 3) & 7)) << 3) + (skey & 7)] = ds[j];
    }
  };

  float m_run[4] = {-1e30f, -1e30f, -1e30f, -1e30f};
  float l_run[4] = {0.f, 0.f, 0.f, 0.f};
  f32x4 oacc[4];
#pragma unroll
  for (int db = 0; db < 4; ++db) oacc[db] = (f32x4){0.f, 0.f, 0.f, 0.f};

  // prologue: Q + K(0) DMA, V(0) regs
#pragma unroll
  for (int i = 0; i < 2; ++i)
    async_copy16(&Qs[(w * 16 + i * 8) * 64], qsrc + (size_t)(i * 8) * DIMN);
  kdma(0, 0);
  vload(va0, va1, 0);
  __syncthreads();

  bf16x8 qf[2];
#pragma unroll
  for (int kh = 0; kh < 2; ++kh) {
    int row = w * 16 + (l & 15);
    int s = (l >> 4) + kh * 4;
    qf[kh] = *(const bf16x8*)&Qs[row * 64 + (s ^ (row & 7)) * 8];
  }

  auto compute = [&](int kbuf) {
    // S = Q K^T
    f32x4 sAcc[4];
#pragma unroll
    for (int nb = 0; nb < 4; ++nb) sAcc[nb] = (f32x4){0.f, 0.f, 0.f, 0.f};
#pragma unroll
    for (int kh = 0; kh < 2; ++kh) {
      bf16x8 kf[4];
#pragma unroll
      for (int nb = 0; nb < 4; ++nb) {
        int row = nb * 16 + (l & 15);
        int s = (l >> 4) + kh * 4;
        kf[nb] = *(const bf16x8*)&Ks[kbuf][row * 64 + (s ^ (row & 7)) * 8];
      }
      __builtin_amdgcn_s_setprio(1);
#pragma unroll
      for (int nb = 0; nb < 4; ++nb) sAcc[nb] = MFMA16(qf[kh], kf[nb], sAcc[nb]);
      __builtin_amdgcn_s_setprio(0);
    }
    // online softmax
    float sc[4], mx[4];
#pragma unroll
    for (int r = 0; r < 4; ++r) {
      float mv = fmaxf(fmaxf(sAcc[0][r], sAcc[1][r]), fmaxf(sAcc[2][r], sAcc[3][r]));
      mv = fmaxf(mv, __shfl_xor(mv, 1));
      mv = fmaxf(mv, __shfl_xor(mv, 2));
      mv = fmaxf(mv, __shfl_xor(mv, 4));
      mv = fmaxf(mv, __shfl_xor(mv, 8));
      float mn = fmaxf(m_run[r], mv);
      sc[r] = __expf(m_run[r] - mn);
      m_run[r] = mn;
      mx[r] = mn;
    }
#pragma unroll
    for (int nb = 0; nb < 4; ++nb) {
      f32x4 sv = sAcc[nb];
#pragma unroll
      for (int r = 0; r < 4; ++r) sv[r] = __expf(sv[r] - mx[r]);
      sAcc[nb] = sv;
    }
#pragma unroll
    for (int r = 0; r < 4; ++r) {
      float ls = sAcc[0][r] + sAcc[1][r] + sAcc[2][r] + sAcc[3][r];
      ls += __shfl_xor(ls, 1);
      ls += __shfl_xor(ls, 2);
      ls += __shfl_xor(ls, 4);
      ls += __shfl_xor(ls, 8);
      l_run[r] = l_run[r] * sc[r] + ls;
    }
#pragma unroll
    for (int db = 0; db < 4; ++db) {
      f32x4 ov = oacc[db];
#pragma unroll
      for (int r = 0; r < 4; ++r) ov[r] *= sc[r];
      oacc[db] = ov;
    }
    // P -> bf16 (cheap pack) -> per-wave LDS
#pragma unroll
    for (int nb = 0; nb < 4; ++nb)
#pragma unroll
      for (int r = 0; r < 4; ++r)
        Ps[w][((l >> 4) * 4 + r) * 72 + nb * 16 + (l & 15)] = f2bf_rhu(sAcc[nb][r]);
    // O += P V (swizzled Vt reads)
#pragma unroll
    for (int kh = 0; kh < 2; ++kh) {
      bf16x8 pf = *(const bf16x8*)&Ps[w][(l & 15) * 72 + (l >> 4) * 8 + kh * 32];
      bf16x8 vf[4];
#pragma unroll
      for (int db = 0; db < 4; ++db) {
        int R = db * 16 + (l & 15);
        int s = (l >> 4) + kh * 4;
        vf[db] = *(const bf16x8*)&Vt[R * 72 + (s ^ ((R >> 3) & 7)) * 8];
      }
      __builtin_amdgcn_s_setprio(1);
#pragma unroll
      for (int db = 0; db < 4; ++db) oacc[db] = MFMA16(pf, vf[db], oacc[db]);
      __builtin_amdgcn_s_setprio(0);
    }
  };

  for (int it = 0; it < 8; ++it) {
    int t0 = 2 * it;
    // tile t0: K resident in Ks[0], V in va
    vwrite(va0, va1);
    __syncthreads();
    kdma(1, t0 + 1);           // prefetch: drains at end-of-tile sync (hidden)
    vload(vb0, vb1, t0 + 1);
    compute(0);
    __syncthreads();
    // tile t0+1: K in Ks[1], V in vb
    vwrite(vb0, vb1);
    __syncthreads();
    if (it < 7) {
      kdma(0, t0 + 2);
      vload(va0, va1, t0 + 2);
    }
    compute(1);
    __syncthreads();
  }

  // epilogue
#pragma unroll
  for (int db = 0; db < 4; ++db)
#pragma unroll
    for (int r = 0; r < 4; ++r) {
      float vl = oacc[db][r] / l_run[r];
      int rg = q0 + w * 16 + (l >> 4) * 4 + r;
      int cg = h * 64 + db * 16 + (l & 15);
      o[(size_t)rg * DIMN + cg] = f2bf(vl);
    }
}

extern "C" void kernel_launch(void* const* d_in, const int* in_sizes, int n_in,
                              void* d_out, int out_size, void* d_ws, size_t ws_size,
                              hipStream_t stream) {
  const float* x  = (const float*)d_in[0];
  const float* wq = (const float*)d_in[1];
  const float* wk = (const float*)d_in[2];
  const float* wv = (const float*)d_in[3];
  const float* wo = (const float*)d_in[4];

  char* ws = (char*)d_ws;
  const size_t MB16 = (size_t)16 * 1024 * 1024;
  unsigned short* xb = (unsigned short*)(ws);
  unsigned short* qb = (unsigned short*)(ws + 1 * MB16);
  unsigned short* kb = (unsigned short*)(ws + 2 * MB16);
  unsigned short* vb = (unsigned short*)(ws + 3 * MB16);
  unsigned short* ab = (unsigned short*)(ws + 4 * MB16);
  unsigned short* Wt = (unsigned short*)(ws + 5 * MB16);  // 128 MB, reused serially

  const size_t WT_BYTES = (size_t)DIMN * DIMN * 2;
  const size_t NEEDED = 5 * MB16 + WT_BYTES;

  cvt_bf16_kernel<<<4096, 256, 0, stream>>>(x, xb);

  if (ws_size >= NEEDED) {
    transpose_cvt_kernel<<<16384, 256, 0, stream>>>(wq, Wt);
    gemm_dma<0><<<512, 256, 0, stream>>>(xb, Wt, qb, 0.125f);  // softmax scale folded
    transpose_cvt_kernel<<<16384, 256, 0, stream>>>(wk, Wt);
    gemm_dma<0><<<512, 256, 0, stream>>>(xb, Wt, kb, 1.0f);
    transpose_cvt_kernel<<<16384, 256, 0, stream>>>(wv, Wt);
    gemm_dma<0><<<512, 256, 0, stream>>>(xb, Wt, vb, 1.0f);
    attn_kernel<<<2048, 256, 0, stream>>>(qb, kb, vb, ab);
    transpose_cvt_kernel<<<16384, 256, 0, stream>>>(wo, Wt);
    gemm_dma<1><<<512, 256, 0, stream>>>(ab, Wt, d_out, 1.0f);
  } else {
    gemm_fb<0><<<512, 256, 0, stream>>>(xb, wq, qb, 0.125f);
    gemm_fb<0><<<512, 256, 0, stream>>>(xb, wk, kb, 1.0f);
    gemm_fb<0><<<512, 256, 0, stream>>>(xb, wv, vb, 1.0f);
    attn_kernel<<<2048, 256, 0, stream>>>(qb, kb, vb, ab);
    gemm_fb<1><<<512, 256, 0, stream>>>(ab, wo, d_out, 1.0f);
  }
}

// Round 14
// 1060.534 us; speedup vs baseline: 1.4527x; 1.0099x over previous
//
#include <hip/hip_runtime.h>

#define DIMN 8192
#define SEQ  1024
#define NHEAD 128

typedef __attribute__((ext_vector_type(8))) short bf16x8;
typedef __attribute__((ext_vector_type(4))) float f32x4;

#define MFMA16(a, b, c) __builtin_amdgcn_mfma_f32_16x16x32_bf16((a), (b), (c), 0, 0, 0)

__device__ __forceinline__ unsigned short f2bf(float f) {
  unsigned u = __float_as_uint(f);
  return (unsigned short)((u + 0x7FFFu + ((u >> 16) & 1u)) >> 16);
}
__device__ __forceinline__ unsigned pack2(float a, float b) {
  return (unsigned)f2bf(a) | ((unsigned)f2bf(b) << 16);
}
__device__ __forceinline__ unsigned pack2_rhu(float lo, float hi) {
  unsigned a = __float_as_uint(lo) + 0x8000u;
  unsigned b = __float_as_uint(hi) + 0x8000u;
  return (a >> 16) | (b & 0xFFFF0000u);
}
__device__ __forceinline__ unsigned short f2bf_rhu(float f) {
  return (unsigned short)((__float_as_uint(f) + 0x8000u) >> 16);
}
__device__ __forceinline__ void async_copy16(void* lds_dst, const void* gsrc) {
  __builtin_amdgcn_global_load_lds(
      (const __attribute__((address_space(1))) unsigned int*)gsrc,
      (__attribute__((address_space(3))) unsigned int*)lds_dst, 16, 0, 0);
}

// ---------------- fp32 -> bf16 convert (x) ----------------
__global__ __launch_bounds__(256) void cvt_bf16_kernel(
    const float* __restrict__ in, unsigned short* __restrict__ out) {
  int i = blockIdx.x * 256 + threadIdx.x;
  const float4* p = (const float4*)in;
  float4 a = p[2 * i];
  float4 b = p[2 * i + 1];
  uint4 r;
  r.x = pack2(a.x, a.y);
  r.y = pack2(a.z, a.w);
  r.z = pack2(b.x, b.y);
  r.w = pack2(b.z, b.w);
  ((uint4*)out)[i] = r;
}

// ------------- W[k][n] fp32 -> Wt[n][k] bf16 (transpose+convert v2) -------------
// R13 DIAGNOSIS: 15.2M bank conflicts (8-way transposed scalar LDS writes +
// degenerate column reads), 1.7 TB/s effective vs ~6.3 achievable.
// V2: phase 1 stores the tile K-MAJOR with b128 writes at k*72 + slot*8 —
// bank base 4(k+slot)%32, distinct across each 8-lane group (the R6 write_B
// shape that measured 0 conflicts). Transpose happens on the READ side:
// phase 2 lane mapping n = 4*((t>>2)&15) + (t>>6) spreads banks so the 16
// scalar column reads are only 4-way (1.58x), then 2 coalesced uint4 global
// writes (4 lanes -> 128B contiguous per Wt row).
__global__ __launch_bounds__(256) void transpose_cvt_kernel(
    const float* __restrict__ W, unsigned short* __restrict__ Wt) {
  __shared__ unsigned short T[64 * 72];  // row k: 64 bf16 + 8 pad (stride 72)
  const int t = threadIdx.x;
  const int k0 = (blockIdx.x & 127) * 64;
  const int n0 = (blockIdx.x >> 7) * 64;
  // phase 1: k-major store, 2 passes (k = t>>3 and +32), slot = t&7
  const int slot = t & 7;
  const int kr = t >> 3;
#pragma unroll
  for (int pass = 0; pass < 2; ++pass) {
    int k = kr + pass * 32;
    const float* src = &W[(size_t)(k0 + k) * DIMN + n0 + slot * 8];
    float4 a = *(const float4*)src;
    float4 b = *(const float4*)(src + 4);
    uint4 r;
    r.x = pack2_rhu(a.x, a.y);
    r.y = pack2_rhu(a.z, a.w);
    r.z = pack2_rhu(b.x, b.y);
    r.w = pack2_rhu(b.z, b.w);
    *(uint4*)&T[k * 72 + slot * 8] = r;
  }
  __syncthreads();
  // phase 2: transposing reads (4-way max), coalesced 32B global writes
  const int n = 4 * ((t >> 2) & 15) + (t >> 6);  // interleaved for bank spread
  const int c = (t & 3) * 16;                    // k-chunk
  unsigned short tmp[16];
#pragma unroll
  for (int j = 0; j < 16; ++j) tmp[j] = T[(c + j) * 72 + n];
  uint4* dst = (uint4*)&Wt[(size_t)(n0 + n) * DIMN + k0 + c];
  dst[0] = *(uint4*)&tmp[0];
  dst[1] = *(uint4*)&tmp[8];
}

// ---------------- pure-DMA GEMM (unchanged from R12, ~150us) ----------------
template <int WRITE_F32>
__global__ __launch_bounds__(256, 2) void gemm_dma(
    const unsigned short* __restrict__ A, const unsigned short* __restrict__ Wt,
    void* __restrict__ Cout, float out_scale) {
  __shared__ unsigned short smem[2 * 16384];
  const int t = threadIdx.x;
  const int l = t & 63;
  const int w = t >> 6;
  const int wm = w >> 1, wn = w & 1;
  const int logical = (blockIdx.x & 7) * 64 + (blockIdx.x >> 3);
  const int m0 = (logical & 7) * 128;
  const int n0 = (logical >> 3) * 128;

  const int rin = l >> 3;
  const int aslot = (l & 7) ^ rin;

  f32x4 acc[4][4];
#pragma unroll
  for (int mb = 0; mb < 4; ++mb)
#pragma unroll
    for (int nb = 0; nb < 4; ++nb) acc[mb][nb] = (f32x4){0.f, 0.f, 0.f, 0.f};

  const unsigned short* aptr = A  + (size_t)(m0 + w * 32 + rin) * DIMN + aslot * 8;
  const unsigned short* bptr = Wt + (size_t)(n0 + w * 32 + rin) * DIMN + aslot * 8;

  auto stage = [&](int buf) {
    unsigned short* sa = &smem[buf * 16384];
    unsigned short* sb = sa + 8192;
#pragma unroll
    for (int i = 0; i < 4; ++i)
      async_copy16(&sa[(w * 32 + i * 8) * 64], aptr + (size_t)i * 8 * DIMN);
#pragma unroll
    for (int i = 0; i < 4; ++i)
      async_copy16(&sb[(w * 32 + i * 8) * 64], bptr + (size_t)i * 8 * DIMN);
    aptr += 64;
    bptr += 64;
  };
  auto compute = [&](int buf) {
    const unsigned short* la = &smem[buf * 16384];
    const unsigned short* lb = la + 8192;
#pragma unroll
    for (int kh = 0; kh < 2; ++kh) {
      bf16x8 af[4], bf[4];
#pragma unroll
      for (int mb = 0; mb < 4; ++mb) {
        int row = wm * 64 + mb * 16 + (l & 15);
        int sl = ((l >> 4) + kh * 4) ^ (row & 7);
        af[mb] = *(const bf16x8*)&la[row * 64 + sl * 8];
      }
#pragma unroll
      for (int nb = 0; nb < 4; ++nb) {
        int row = wn * 64 + nb * 16 + (l & 15);
        int sl = ((l >> 4) + kh * 4) ^ (row & 7);
        bf[nb] = *(const bf16x8*)&lb[row * 64 + sl * 8];
      }
      __builtin_amdgcn_s_setprio(1);
#pragma unroll
      for (int mb = 0; mb < 4; ++mb)
#pragma unroll
        for (int nb = 0; nb < 4; ++nb)
          acc[mb][nb] = MFMA16(af[mb], bf[nb], acc[mb][nb]);
      __builtin_amdgcn_s_setprio(0);
    }
  };

  stage(0);
  __syncthreads();
  int buf = 0;
  for (int kt = 0; kt < 128; ++kt) {
    if (kt < 127) stage(buf ^ 1);
    compute(buf);
    __syncthreads();
    buf ^= 1;
  }

#pragma unroll
  for (int mb = 0; mb < 4; ++mb)
#pragma unroll
    for (int nb = 0; nb < 4; ++nb)
#pragma unroll
      for (int r = 0; r < 4; ++r) {
        int rg = m0 + wm * 64 + mb * 16 + (l >> 4) * 4 + r;
        int cg = n0 + wn * 64 + nb * 16 + (l & 15);
        float vl = acc[mb][nb][r] * out_scale;
        if (WRITE_F32)
          ((float*)Cout)[(size_t)rg * DIMN + cg] = vl;
        else
          ((unsigned short*)Cout)[(size_t)rg * DIMN + cg] = f2bf(vl);
      }
}

// ---------------- fallback GEMM (R11 reg-staging) — used only if ws too small ----
template <int WRITE_F32>
__global__ __launch_bounds__(256, 3) void gemm_fb(
    const unsigned short* __restrict__ A, const float* __restrict__ W,
    void* __restrict__ Cout, float out_scale) {
  __shared__ unsigned short smem[2 * 8192];
  const int t = threadIdx.x;
  const int l = t & 63;
  const int w = t >> 6;
  const int wm = w >> 1, wn = w & 1;
  const int logical = (blockIdx.x & 7) * 64 + (blockIdx.x >> 3);
  const int m0 = (logical & 7) * 128;
  const int n0 = (logical >> 3) * 128;
  const int arow = l >> 2;
  const int aslot = l & 3;
  const int bn = t & 127;
  const int bkb = (t >> 7) * 16;

  f32x4 acc[4][4];
#pragma unroll
  for (int mb = 0; mb < 4; ++mb)
#pragma unroll
    for (int nb = 0; nb < 4; ++nb) acc[mb][nb] = (f32x4){0.f, 0.f, 0.f, 0.f};

  float fb[16];
  const unsigned short* aptr = A + (size_t)(m0 + w * 32 + arow) * DIMN + aslot * 8;
  const float* wp = W + (size_t)bkb * DIMN + n0 + bn;

  auto load_B = [&]() {
#pragma unroll
    for (int i = 0; i < 16; ++i) fb[i] = wp[(size_t)i * DIMN];
    wp += (size_t)32 * DIMN;
  };
  auto write_B = [&](int buf) {
    unsigned short* bb = &smem[buf * 8192 + 4096];
    const int ps = (bn >> 1) & 3;
#pragma unroll
    for (int j = 0; j < 2; ++j) {
      int p = ((bkb >> 3) + j) ^ ps;
      uint4 val;
      val.x = pack2_rhu(fb[j * 8 + 0], fb[j * 8 + 1]);
      val.y = pack2_rhu(fb[j * 8 + 2], fb[j * 8 + 3]);
      val.z = pack2_rhu(fb[j * 8 + 4], fb[j * 8 + 5]);
      val.w = pack2_rhu(fb[j * 8 + 6], fb[j * 8 + 7]);
      *(uint4*)&bb[bn * 32 + p * 8] = val;
    }
  };
  auto stage_A = [&](int buf) {
#pragma unroll
    for (int i = 0; i < 2; ++i)
      async_copy16(&smem[buf * 8192 + (w * 32 + i * 16) * 32],
                   aptr + (size_t)i * 16 * DIMN);
    aptr += 32;
  };
  auto compute = [&](int buf) {
    const unsigned short* la = &smem[buf * 8192];
    const unsigned short* lb = la + 4096;
    bf16x8 af[4], bf[4];
#pragma unroll
    for (int mb = 0; mb < 4; ++mb) {
      int row = wm * 64 + mb * 16 + (l & 15);
      af[mb] = *(const bf16x8*)&la[row * 32 + (l >> 4) * 8];
    }
#pragma unroll
    for (int nb = 0; nb < 4; ++nb) {
      int row = wn * 64 + nb * 16 + (l & 15);
      int p = (l >> 4) ^ ((row >> 1) & 3);
      bf[nb] = *(const bf16x8*)&lb[row * 32 + p * 8];
    }
#pragma unroll
    for (int mb = 0; mb < 4; ++mb)
#pragma unroll
      for (int nb = 0; nb < 4; ++nb)
        acc[mb][nb] = MFMA16(af[mb], bf[nb], acc[mb][nb]);
  };

  load_B();
  stage_A(0);
  write_B(0);
  __syncthreads();
  int buf = 0;
  for (int kt = 0; kt < 256; ++kt) {
    if (kt < 255) {
      load_B();
      stage_A(buf ^ 1);
    }
    compute(buf);
    if (kt < 255) write_B(buf ^ 1);
    __syncthreads();
    buf ^= 1;
  }
#pragma unroll
  for (int mb = 0; mb < 4; ++mb)
#pragma unroll
    for (int nb = 0; nb < 4; ++nb)
#pragma unroll
      for (int r = 0; r < 4; ++r) {
        int rg = m0 + wm * 64 + mb * 16 + (l >> 4) * 4 + r;
        int cg = n0 + wn * 64 + nb * 16 + (l & 15);
        float vl = acc[mb][nb][r] * out_scale;
        if (WRITE_F32)
          ((float*)Cout)[(size_t)rg * DIMN + cg] = vl;
        else
          ((unsigned short*)Cout)[(size_t)rg * DIMN + cg] = f2bf(vl);
      }
}

// ---------------- fused flash attention v2 (unchanged from R13) ----------------
__global__ __launch_bounds__(256) void attn_kernel(
    const unsigned short* __restrict__ q, const unsigned short* __restrict__ k,
    const unsigned short* __restrict__ v, unsigned short* __restrict__ o) {
  __shared__ unsigned short Qs[64 * 64];
  __shared__ unsigned short Ks[2][64 * 64];
  __shared__ unsigned short Vt[64 * 72];
  __shared__ unsigned short Ps[4][16 * 72];

  const int t = threadIdx.x, l = t & 63, w = t >> 6;
  const int logical = (blockIdx.x & 7) * 256 + (blockIdx.x >> 3);  // XCD swizzle
  const int h = logical >> 4;
  const int q0 = (logical & 15) * 64;

  const int rin = l >> 3;
  const int aslot = (l & 7) ^ rin;
  const int skey = t >> 2;
  const int sd = (t & 3) * 16;

  const unsigned short* qsrc = q + (size_t)(q0 + w * 16 + rin) * DIMN + h * 64 + aslot * 8;
  const unsigned short* ksrc = k + (size_t)(w * 16 + rin) * DIMN + h * 64 + aslot * 8;
  const unsigned short* vsrc = v + (size_t)skey * DIMN + h * 64 + sd;

  auto kdma = [&](int buf, int kv) {
#pragma unroll
    for (int i = 0; i < 2; ++i)
      async_copy16(&Ks[buf][(w * 16 + i * 8) * 64],
                   ksrc + (size_t)(kv * 64 + i * 8) * DIMN);
  };
  uint4 va0, va1, vb0, vb1;
  auto vload = [&](uint4& r0, uint4& r1, int kv) {
    const unsigned short* p = vsrc + (size_t)(kv * 64) * DIMN;
    r0 = *(const uint4*)p;
    r1 = *(const uint4*)(p + 8);
  };
  auto vwrite = [&](const uint4& r0, const uint4& r1) {
    const unsigned short* cs = (const unsigned short*)&r0;
    const unsigned short* ds = (const unsigned short*)&r1;
#pragma unroll
    for (int j = 0; j < 8; ++j) {
      int row = sd + j;
      Vt[row * 72 + (((skey >> 3) ^ ((row >> 3) & 7)) << 3) + (skey & 7)] = cs[j];
    }
#pragma unroll
    for (int j = 0; j < 8; ++j) {
      int row = sd + 8 + j;
      Vt[row * 72 + (((skey >> 3) ^ ((row >> 3) & 7)) << 3) + (skey & 7)] = ds[j];
    }
  };

  float m_run[4] = {-1e30f, -1e30f, -1e30f, -1e30f};
  float l_run[4] = {0.f, 0.f, 0.f, 0.f};
  f32x4 oacc[4];
#pragma unroll
  for (int db = 0; db < 4; ++db) oacc[db] = (f32x4){0.f, 0.f, 0.f, 0.f};

#pragma unroll
  for (int i = 0; i < 2; ++i)
    async_copy16(&Qs[(w * 16 + i * 8) * 64], qsrc + (size_t)(i * 8) * DIMN);
  kdma(0, 0);
  vload(va0, va1, 0);
  __syncthreads();

  bf16x8 qf[2];
#pragma unroll
  for (int kh = 0; kh < 2; ++kh) {
    int row = w * 16 + (l & 15);
    int s = (l >> 4) + kh * 4;
    qf[kh] = *(const bf16x8*)&Qs[row * 64 + (s ^ (row & 7)) * 8];
  }

  auto compute = [&](int kbuf) {
    f32x4 sAcc[4];
#pragma unroll
    for (int nb = 0; nb < 4; ++nb) sAcc[nb] = (f32x4){0.f, 0.f, 0.f, 0.f};
#pragma unroll
    for (int kh = 0; kh < 2; ++kh) {
      bf16x8 kf[4];
#pragma unroll
      for (int nb = 0; nb < 4; ++nb) {
        int row = nb * 16 + (l & 15);
        int s = (l >> 4) + kh * 4;
        kf[nb] = *(const bf16x8*)&Ks[kbuf][row * 64 + (s ^ (row & 7)) * 8];
      }
      __builtin_amdgcn_s_setprio(1);
#pragma unroll
      for (int nb = 0; nb < 4; ++nb) sAcc[nb] = MFMA16(qf[kh], kf[nb], sAcc[nb]);
      __builtin_amdgcn_s_setprio(0);
    }
    float sc[4], mx[4];
#pragma unroll
    for (int r = 0; r < 4; ++r) {
      float mv = fmaxf(fmaxf(sAcc[0][r], sAcc[1][r]), fmaxf(sAcc[2][r], sAcc[3][r]));
      mv = fmaxf(mv, __shfl_xor(mv, 1));
      mv = fmaxf(mv, __shfl_xor(mv, 2));
      mv = fmaxf(mv, __shfl_xor(mv, 4));
      mv = fmaxf(mv, __shfl_xor(mv, 8));
      float mn = fmaxf(m_run[r], mv);
      sc[r] = __expf(m_run[r] - mn);
      m_run[r] = mn;
      mx[r] = mn;
    }
#pragma unroll
    for (int nb = 0; nb < 4; ++nb) {
      f32x4 sv = sAcc[nb];
#pragma unroll
      for (int r = 0; r < 4; ++r) sv[r] = __expf(sv[r] - mx[r]);
      sAcc[nb] = sv;
    }
#pragma unroll
    for (int r = 0; r < 4; ++r) {
      float ls = sAcc[0][r] + sAcc[1][r] + sAcc[2][r] + sAcc[3][r];
      ls += __shfl_xor(ls, 1);
      ls += __shfl_xor(ls, 2);
      ls += __shfl_xor(ls, 4);
      ls += __shfl_xor(ls, 8);
      l_run[r] = l_run[r] * sc[r] + ls;
    }
#pragma unroll
    for (int db = 0; db < 4; ++db) {
      f32x4 ov = oacc[db];
#pragma unroll
      for (int r = 0; r < 4; ++r) ov[r] *= sc[r];
      oacc[db] = ov;
    }
#pragma unroll
    for (int nb = 0; nb < 4; ++nb)
#pragma unroll
      for (int r = 0; r < 4; ++r)
        Ps[w][((l >> 4) * 4 + r) * 72 + nb * 16 + (l & 15)] = f2bf_rhu(sAcc[nb][r]);
#pragma unroll
    for (int kh = 0; kh < 2; ++kh) {
      bf16x8 pf = *(const bf16x8*)&Ps[w][(l & 15) * 72 + (l >> 4) * 8 + kh * 32];
      bf16x8 vf[4];
#pragma unroll
      for (int db = 0; db < 4; ++db) {
        int R = db * 16 + (l & 15);
        int s = (l >> 4) + kh * 4;
        vf[db] = *(const bf16x8*)&Vt[R * 72 + (s ^ ((R >> 3) & 7)) * 8];
      }
      __builtin_amdgcn_s_setprio(1);
#pragma unroll
      for (int db = 0; db < 4; ++db) oacc[db] = MFMA16(pf, vf[db], oacc[db]);
      __builtin_amdgcn_s_setprio(0);
    }
  };

  for (int it = 0; it < 8; ++it) {
    int t0 = 2 * it;
    vwrite(va0, va1);
    __syncthreads();
    kdma(1, t0 + 1);
    vload(vb0, vb1, t0 + 1);
    compute(0);
    __syncthreads();
    vwrite(vb0, vb1);
    __syncthreads();
    if (it < 7) {
      kdma(0, t0 + 2);
      vload(va0, va1, t0 + 2);
    }
    compute(1);
    __syncthreads();
  }

#pragma unroll
  for (int db = 0; db < 4; ++db)
#pragma unroll
    for (int r = 0; r < 4; ++r) {
      float vl = oacc[db][r] / l_run[r];
      int rg = q0 + w * 16 + (l >> 4) * 4 + r;
      int cg = h * 64 + db * 16 + (l & 15);
      o[(size_t)rg * DIMN + cg] = f2bf(vl);
    }
}

extern "C" void kernel_launch(void* const* d_in, const int* in_sizes, int n_in,
                              void* d_out, int out_size, void* d_ws, size_t ws_size,
                              hipStream_t stream) {
  const float* x  = (const float*)d_in[0];
  const float* wq = (const float*)d_in[1];
  const float* wk = (const float*)d_in[2];
  const float* wv = (const float*)d_in[3];
  const float* wo = (const float*)d_in[4];

  char* ws = (char*)d_ws;
  const size_t MB16 = (size_t)16 * 1024 * 1024;
  unsigned short* xb = (unsigned short*)(ws);
  unsigned short* qb = (unsigned short*)(ws + 1 * MB16);
  unsigned short* kb = (unsigned short*)(ws + 2 * MB16);
  unsigned short* vb = (unsigned short*)(ws + 3 * MB16);
  unsigned short* ab = (unsigned short*)(ws + 4 * MB16);
  unsigned short* Wt = (unsigned short*)(ws + 5 * MB16);  // 128 MB, reused serially

  const size_t WT_BYTES = (size_t)DIMN * DIMN * 2;
  const size_t NEEDED = 5 * MB16 + WT_BYTES;

  cvt_bf16_kernel<<<4096, 256, 0, stream>>>(x, xb);

  if (ws_size >= NEEDED) {
    transpose_cvt_kernel<<<16384, 256, 0, stream>>>(wq, Wt);
    gemm_dma<0><<<512, 256, 0, stream>>>(xb, Wt, qb, 0.125f);  // softmax scale folded
    transpose_cvt_kernel<<<16384, 256, 0, stream>>>(wk, Wt);
    gemm_dma<0><<<512, 256, 0, stream>>>(xb, Wt, kb, 1.0f);
    transpose_cvt_kernel<<<16384, 256, 0, stream>>>(wv, Wt);
    gemm_dma<0><<<512, 256, 0, stream>>>(xb, Wt, vb, 1.0f);
    attn_kernel<<<2048, 256, 0, stream>>>(qb, kb, vb, ab);
    transpose_cvt_kernel<<<16384, 256, 0, stream>>>(wo, Wt);
    gemm_dma<1><<<512, 256, 0, stream>>>(ab, Wt, d_out, 1.0f);
  } else {
    gemm_fb<0><<<512, 256, 0, stream>>>(xb, wq, qb, 0.125f);
    gemm_fb<0><<<512, 256, 0, stream>>>(xb, wk, kb, 1.0f);
    gemm_fb<0><<<512, 256, 0, stream>>>(xb, wv, vb, 1.0f);
    attn_kernel<<<2048, 256, 0, stream>>>(qb, kb, vb, ab);
    gemm_fb<1><<<512, 256, 0, stream>>>(ab, wo, d_out, 1.0f);
  }
}